// Round 12
// baseline (565.616 us; speedup 1.0000x reference)
//
#include <hip/hip_runtime.h>
#include <hip/hip_fp16.h>

// CANPathIntegrator — R17: two-set software pipeline over the MALL exchange.
//
// R16 post-mortem: 380us, VALU 28.6%, MFMA 21.4% — neither pipe saturated;
// ~1.5us/step is the serial exchange window (publish -> MALL -> poll ->
// owner) + skew, with nothing overlapping it. Batches are independent, so:
// split the 8 batches into sets A(0-3)/B(4-7) and pipeline:
//   P1A,P2A,pubA | consB(t-1),ownerB | P1B,P2B,pubB | consA(t),ownerA
// Each set's MALL latency+skew hides under the other set's compute; only
// the raw poll-read latency stays serial. Same geometry (64 groups x 4
// slices, K=128), same f16x2 split-precision MFMA (absmax-verified R16),
// same packed-u64 data-as-flag exchange (R14), same part-buffer size
// (2 sets x 8 vals = 16 vals/slice -> 64KB total, same ws need as R16).
// B-fragment now mirrors 4 batches x4 (mask cB>=4); zh stride 536
// (268 dw = 12 mod 32) spreads B-load banks.

typedef __attribute__((ext_vector_type(8))) _Float16 half8;
typedef __attribute__((ext_vector_type(4))) float f32x4;

namespace {
constexpr int NT = 128;
constexpr int DD = 512;
constexpr int KP = 256;
constexpr int NS = 4;      // row slices (128 rows each)
constexpr int NG = 64;     // batch groups
constexpr int NB = 8;      // batches per group (2 sets of 4)
constexpr int NBLK = NG * NS;   // 256 = #CUs
constexpr int ZST = 536;   // zh/zl row stride (shorts); 268 dw = 12 mod 32
constexpr size_t SETQW   = (size_t)2 * NG * NS * 8;        // u64 per set buf
constexpr size_t PART_BYTES = 2 * SETQW * 8;               // 64 KB total
constexpr size_t A16_BYTES  = (size_t)DD * DD * 2;         // 512 KB each
constexpr float LOSC = 1.0f / 2048.0f;
constexpr float DXSC = 0.1f / 16777216.0f;    // 0.1 * 2^-24

__device__ __forceinline__ int rofs(int r) {   // f32-fallback swizzle
    return 12 * r + 4 * ((r >> 3) & 7) + 32 * (r >> 6);
}
}

// ======================= MFMA pipelined path ==========================

struct __align__(16) ShmP {
    unsigned short zh[4][ZST];    //  4288 B  f16 hi of 256*zx (one set)
    unsigned short zl[4][ZST];    //  4288 B  f16 lo (x2048 residual)
    float2 dpi[NB][NT];           //  8192 B
    float2 om[KP];                //  2048 B
    float2 v[KP];                 //  2048 B  z0hat * 256
    float  wred[16][8];           //   512 B
    float  Sh[NT][NB][2];         //  8192 B
    float  xh[NT][NB][2];         //  8192 B
    float2 x[NB];                 //    64 B
    float  nred[16];              //    64 B
    float  pad[11100];            // 44400 B -> 82288 B total: 1 block/CU
};

__global__ __launch_bounds__(512) void conv_a(
    const float* __restrict__ A,
    unsigned short* __restrict__ Ah, unsigned short* __restrict__ Al)
{
    int i = blockIdx.x * 512 + threadIdx.x;
    float a = A[i] * 256.0f;
    __half h = __float2half(a);
    float r = (a - __half2float(h)) * 2048.0f;
    Ah[i] = __half_as_ushort(h);
    Al[i] = __half_as_ushort(__float2half(r));
}

__attribute__((amdgpu_flat_work_group_size(1024, 1024),
               amdgpu_waves_per_eu(4, 4)))
__global__ void can_mfma(
    const float* __restrict__ dx_pi, const float* __restrict__ z0,
    const float* __restrict__ x0, const float* __restrict__ omega,
    const float* __restrict__ z0b, float* __restrict__ d_out,
    unsigned long long* __restrict__ part,
    const unsigned short* __restrict__ Ah,
    const unsigned short* __restrict__ Al)
{
    __shared__ ShmP sh;
    const int tid = threadIdx.x;
    const int g   = blockIdx.x >> 2;
    const int s   = blockIdx.x & 3;
    const int b0  = NB * g;

    float* z_seq = d_out;
    float* x_seq = d_out + (size_t)512 * NT * DD;

    if (dx_pi == nullptr) ((volatile float*)sh.pad)[0] = 1.f;

    {
        int bb = tid >> 7, tt = tid & 127;
        sh.dpi[bb][tt] =
            reinterpret_cast<const float2*>(dx_pi)[(size_t)(b0 + bb) * NT + tt];
    }
    if (tid < KP) sh.om[tid] = reinterpret_cast<const float2*>(omega)[tid];

    float sq = 0.f;
    if (tid < DD) { float f = z0b[tid]; sq = f * f; }
    #pragma unroll
    for (int o = 1; o < 64; o <<= 1) sq += __shfl_xor(sq, o, 64);
    if ((tid & 63) == 0) sh.nred[tid >> 6] = sq;
    __syncthreads();
    float nsq = 0.f;
    #pragma unroll
    for (int w2 = 0; w2 < 16; ++w2) nsq += sh.nred[w2];
    const float zs = 256.0f / (sqrtf(nsq) + 1e-5f);
    if (tid < KP) {
        float2 vv = reinterpret_cast<const float2*>(z0b)[tid];
        sh.v[tid] = make_float2(vv.x * zs, vv.y * zs);
    }

    // owner state: thread v<8 owns (b = v&3 of each set, comp = v>>2)
    float xrA = 0.f, SrA = 0.f, xrB = 0.f, SrB = 0.f;
    if (tid < 8) {
        int b = tid & 3, comp = tid >> 2;
        xrA = x0[(size_t)(b0 + b) * 2 + comp];
        xrB = x0[(size_t)(b0 + 4 + b) * 2 + comp];
        reinterpret_cast<float*>(&sh.x[b])[comp] = xrA;
        reinterpret_cast<float*>(&sh.x[4 + b])[comp] = xrB;
    }
    __syncthreads();

    // MFMA roles
    const int w   = tid >> 6;          // wave -> M-tiles 2w, 2w+1
    const int l   = tid & 63;
    const int cB  = l & 15;
    const int kg  = l >> 4;
    const int bB4 = l & 3;             // batch within set (x4 mirrored)
    const int mt0 = 2 * w;
    const unsigned short* AhP =
        Ah + (size_t)(16 * mt0 + cB) * DD + (128 * s + 8 * kg);
    const unsigned short* AlP =
        Al + (size_t)(16 * mt0 + cB) * DD + (128 * s + 8 * kg);

    unsigned long long* const pA = part;
    unsigned long long* const pB = part + SETQW;

    for (int t = 0; t < NT; ++t) {
        #pragma unroll
        for (int half = 0; half < 2; ++half) {
            const int off = half * 4;                // set offset 0 / 4

            // ---- P1(set): zx rows 2k1,2k1+1 for batch off+bq ----
            {
                int k1 = tid >> 2, bq = tid & 3;
                float2 o2 = sh.om[k1];
                float2 vv = sh.v[k1];
                float2 xb = sh.x[off + bq];
                float th = o2.x * xb.x + o2.y * xb.y;
                float sn, cs;
                __sincosf(th, &sn, &cs);
                float za  = cs * vv.x - sn * vv.y;
                float zb2 = sn * vv.x + cs * vv.y;
                __half h0 = __float2half(za);
                __half h1 = __float2half(zb2);
                unsigned l0 = __half_as_ushort(
                    __float2half((za - __half2float(h0)) * 2048.f));
                unsigned l1 = __half_as_ushort(
                    __float2half((zb2 - __half2float(h1)) * 2048.f));
                *reinterpret_cast<unsigned*>(&sh.zh[bq][2 * k1]) =
                    (unsigned)__half_as_ushort(h0) |
                    ((unsigned)__half_as_ushort(h1) << 16);
                *reinterpret_cast<unsigned*>(&sh.zl[bq][2 * k1]) =
                    l0 | (l1 << 16);
            }
            __syncthreads();

            // ---- P2(set): split-precision MFMA matvec ----
            f32x4 ac1[2] = {{0.f,0.f,0.f,0.f},{0.f,0.f,0.f,0.f}};
            f32x4 ac2[2] = {{0.f,0.f,0.f,0.f},{0.f,0.f,0.f,0.f}};
            #pragma unroll
            for (int kt = 0; kt < 4; ++kt) {
                int rg = 128 * s + 32 * kt + 8 * kg;
                half8 bh = *reinterpret_cast<const half8*>(&sh.zh[bB4][rg]);
                half8 bl = *reinterpret_cast<const half8*>(&sh.zl[bB4][rg]);
                #pragma unroll
                for (int mi = 0; mi < 2; ++mi) {
                    half8 ah = *reinterpret_cast<const half8*>(
                                   AhP + (size_t)mi * 16 * DD + 32 * kt);
                    half8 al = *reinterpret_cast<const half8*>(
                                   AlP + (size_t)mi * 16 * DD + 32 * kt);
                    ac1[mi] = __builtin_amdgcn_mfma_f32_16x16x32_f16(
                                  ah, bh, ac1[mi], 0, 0, 0);
                    ac2[mi] = __builtin_amdgcn_mfma_f32_16x16x32_f16(
                                  al, bh, ac2[mi], 0, 0, 0);
                    ac2[mi] = __builtin_amdgcn_mfma_f32_16x16x32_f16(
                                  ah, bl, ac2[mi], 0, 0, 0);
                }
            }

            // ---- contract in-register (linear in w) ----
            float d0 = 0.f, d1 = 0.f;
            #pragma unroll
            for (int mi = 0; mi < 2; ++mi) {
                int cb = 16 * (mt0 + mi) + 4 * kg;
                float wv0 = fmaf(ac2[mi][0], LOSC, ac1[mi][0]);
                float wv1 = fmaf(ac2[mi][1], LOSC, ac1[mi][1]);
                float wv2 = fmaf(ac2[mi][2], LOSC, ac1[mi][2]);
                float wv3 = fmaf(ac2[mi][3], LOSC, ac1[mi][3]);
                uint2 zhp = *reinterpret_cast<const uint2*>(&sh.zh[bB4][cb]);
                uint2 zlp = *reinterpret_cast<const uint2*>(&sh.zl[bB4][cb]);
                float z0v = fmaf(__half2float(__ushort_as_half(
                                     (unsigned short)(zlp.x & 0xffff))), LOSC,
                                 __half2float(__ushort_as_half(
                                     (unsigned short)(zhp.x & 0xffff))));
                float z1v = fmaf(__half2float(__ushort_as_half(
                                     (unsigned short)(zlp.x >> 16))), LOSC,
                                 __half2float(__ushort_as_half(
                                     (unsigned short)(zhp.x >> 16))));
                float z2v = fmaf(__half2float(__ushort_as_half(
                                     (unsigned short)(zlp.y & 0xffff))), LOSC,
                                 __half2float(__ushort_as_half(
                                     (unsigned short)(zhp.y & 0xffff))));
                float z3v = fmaf(__half2float(__ushort_as_half(
                                     (unsigned short)(zlp.y >> 16))), LOSC,
                                 __half2float(__ushort_as_half(
                                     (unsigned short)(zhp.y >> 16))));
                float g0 = fmaf(wv1, z0v, -wv0 * z1v);
                float g1 = fmaf(wv3, z2v, -wv2 * z3v);
                float4 omq = *reinterpret_cast<const float4*>(&sh.om[cb >> 1]);
                d0 = fmaf(g0, omq.x, d0); d1 = fmaf(g0, omq.y, d1);
                d0 = fmaf(g1, omq.z, d0); d1 = fmaf(g1, omq.w, d1);
            }
            if (cB >= 4) { d0 = 0.f; d1 = 0.f; }   // mask mirrored copies

            d0 += __shfl_xor(d0, 16, 64);  d0 += __shfl_xor(d0, 32, 64);
            d1 += __shfl_xor(d1, 16, 64);  d1 += __shfl_xor(d1, 32, 64);
            if (l < 4) {                    // value v = comp*4 + b
                sh.wred[w][l]     = d0;
                sh.wred[w][l + 4] = d1;
            }
            __syncthreads();

            // ---- publish this set's step-t partial ----
            unsigned long long* pub = half ? pB : pA;
            if (tid < 8) {
                float ssum = 0.f;
                #pragma unroll
                for (int w2 = 0; w2 < 16; ++w2) ssum += sh.wred[w2][tid];
                unsigned long long pk =
                    (((unsigned long long)(unsigned)(t + 1)) << 32) |
                    (unsigned long long)__float_as_uint(ssum);
                __hip_atomic_store(
                    pub + ((size_t)(t & 1) * NG + g) * (NS * 8) + s * 8 + tid,
                    pk, __ATOMIC_RELAXED, __HIP_MEMORY_SCOPE_AGENT);
            }

            // ---- consume the OTHER set (latency hidden by this compute) ----
            // half 0: consume B(t-1) [skip at t=0]; half 1: consume A(t)
            const int tc = half ? t : t - 1;
            if (tc >= 0) {
                unsigned long long* con = half ? pA : pB;
                float val = 0.f;
                if (tid < 32) {
                    int sl = tid >> 3, v = tid & 7;
                    unsigned long long* addr =
                        con + ((size_t)(tc & 1) * NG + g) * (NS * 8)
                            + sl * 8 + v;
                    const unsigned long long tgt =
                        ((unsigned long long)(unsigned)(tc + 1)) << 32;
                    unsigned long long pk;
                    for (;;) {
                        pk = __hip_atomic_load(addr, __ATOMIC_RELAXED,
                                               __HIP_MEMORY_SCOPE_AGENT);
                        if (pk >= tgt) break;
                        __builtin_amdgcn_s_sleep(1);
                    }
                    val = __uint_as_float((unsigned)(pk & 0xffffffffull));
                    val += __shfl_xor(val, 8, 64);
                    val += __shfl_xor(val, 16, 64);
                }
                if (tid < 8) {
                    int b = tid & 3, comp = tid >> 2;
                    int ob = half ? b : 4 + b;       // half0 updates set B...
                    // half==0 consumes A? No: half0 consumes B(t-1); the
                    // owner for that set is B. half1 consumes A(t)->owner A.
                    float pi = reinterpret_cast<const float*>(
                                   &sh.dpi[half ? b : 4 + b][tc])[comp];
                    float dtv = fmaf(DXSC, val, pi);
                    if (half) {          // owner A (consumed A(t))
                        SrA += dtv;
                        xrA = fminf(fmaxf(xrA + dtv, 0.f), 2.0f);
                        reinterpret_cast<float*>(&sh.x[b])[comp] = xrA;
                        sh.Sh[tc][b][comp] = SrA;
                        sh.xh[tc][b][comp] = xrA;
                    } else {             // owner B (consumed B(t-1))
                        SrB += dtv;
                        xrB = fminf(fmaxf(xrB + dtv, 0.f), 2.0f);
                        reinterpret_cast<float*>(&sh.x[4 + b])[comp] = xrB;
                        sh.Sh[tc][4 + b][comp] = SrB;
                        sh.xh[tc][4 + b][comp] = xrB;
                    }
                    (void)ob;
                }
            }
            __syncthreads();
        }
    }

    // ---- tail: consume B(NT-1), owner B ----
    {
        const int tc = NT - 1;
        float val = 0.f;
        if (tid < 32) {
            int sl = tid >> 3, v = tid & 7;
            unsigned long long* addr =
                pB + ((size_t)(tc & 1) * NG + g) * (NS * 8) + sl * 8 + v;
            const unsigned long long tgt =
                ((unsigned long long)(unsigned)(tc + 1)) << 32;
            unsigned long long pk;
            for (;;) {
                pk = __hip_atomic_load(addr, __ATOMIC_RELAXED,
                                       __HIP_MEMORY_SCOPE_AGENT);
                if (pk >= tgt) break;
                __builtin_amdgcn_s_sleep(1);
            }
            val = __uint_as_float((unsigned)(pk & 0xffffffffull));
            val += __shfl_xor(val, 8, 64);
            val += __shfl_xor(val, 16, 64);
        }
        if (tid < 8) {
            int b = tid & 3, comp = tid >> 2;
            float pi = reinterpret_cast<const float*>(
                           &sh.dpi[4 + b][tc])[comp];
            float dtv = fmaf(DXSC, val, pi);
            SrB += dtv;
            xrB = fminf(fmaxf(xrB + dtv, 0.f), 2.0f);
            sh.Sh[tc][4 + b][comp] = SrB;
            sh.xh[tc][4 + b][comp] = xrB;
        }
    }
    __syncthreads();

    // ---- epilogue: z_seq[b][t][slice cols] = R(omega@S_t) z0[b] ----
    {
        int th2 = tid >> 9, b = (tid >> 6) & 7, kk = tid & 63;
        float2 zp = reinterpret_cast<const float2*>(z0)
                        [(size_t)(b0 + b) * KP + 64 * s + kk];
        float2 o2 = sh.om[64 * s + kk];
        float2* zout = reinterpret_cast<float2*>(z_seq)
                       + (size_t)(b0 + b) * NT * KP + (64 * s + kk);
        for (int tt2 = th2 * 64, e = th2 * 64 + 64; tt2 < e; ++tt2) {
            float Sx = sh.Sh[tt2][b][0], Sy = sh.Sh[tt2][b][1];
            float th = o2.x * Sx + o2.y * Sy;
            float sn, cs;
            __sincosf(th, &sn, &cs);
            zout[(size_t)tt2 * KP] =
                make_float2(cs * zp.x - sn * zp.y, sn * zp.x + cs * zp.y);
        }
    }
    if (s == 0) {
        int b = tid >> 7, tt3 = tid & 127;
        float2 xv = *reinterpret_cast<const float2*>(&sh.xh[tt3][b][0]);
        reinterpret_cast<float2*>(x_seq)[(size_t)(b0 + b) * NT + tt3] = xv;
    }
}

// =================== f32 fallback path (R14, proven) ===================

struct __align__(16) ShmF {
    float  zxc[6400];
    float2 dpi[NB][NT];
    float2 om[KP];
    float2 v[KP];
    float  wred[16][16];
    float  Sh[NT][NB][2];
    float  xh[NT][NB][2];
    float2 x[NB];
    float  nred[16];
    float  pad[7168];
};

__attribute__((amdgpu_flat_work_group_size(1024, 1024),
               amdgpu_waves_per_eu(4, 4)))
__global__ void can_f32(
    const float* __restrict__ dx_pi, const float* __restrict__ z0,
    const float* __restrict__ x0, const float* __restrict__ omega,
    const float* __restrict__ A, const float* __restrict__ z0b,
    float* __restrict__ d_out,
    unsigned long long* __restrict__ part)
{
    __shared__ ShmF sh;
    const int tid = threadIdx.x;
    const int g   = blockIdx.x >> 2;
    const int s   = blockIdx.x & 3;
    const int b0  = NB * g;

    float* z_seq = d_out;
    float* x_seq = d_out + (size_t)512 * NT * DD;

    if (dx_pi == nullptr) ((volatile float*)sh.pad)[0] = 1.f;

    {
        int bb = tid >> 7, tt = tid & 127;
        sh.dpi[bb][tt] =
            reinterpret_cast<const float2*>(dx_pi)[(size_t)(b0 + bb) * NT + tt];
    }
    if (tid < KP) sh.om[tid] = reinterpret_cast<const float2*>(omega)[tid];

    float sq = 0.f;
    if (tid < DD) { float f = z0b[tid]; sq = f * f; }
    #pragma unroll
    for (int o = 1; o < 64; o <<= 1) sq += __shfl_xor(sq, o, 64);
    if ((tid & 63) == 0) sh.nred[tid >> 6] = sq;
    __syncthreads();
    float nsq = 0.f;
    #pragma unroll
    for (int w = 0; w < 16; ++w) nsq += sh.nred[w];
    const float zinv = 1.0f / (sqrtf(nsq) + 1e-5f);
    if (tid < KP) {
        float2 vv = reinterpret_cast<const float2*>(z0b)[tid];
        sh.v[tid] = make_float2(vv.x * zinv, vv.y * zinv);
    }

    float xreg = 0.f, Sreg = 0.f;
    if (tid < 16) {
        int b = tid & 7, comp = tid >> 3;
        xreg = x0[(size_t)(b0 + b) * 2 + comp];
        reinterpret_cast<float*>(&sh.x[b])[comp] = xreg;
    }
    __syncthreads();

    const int rq  = tid >> 6;
    const int cq  = tid & 63;
    const int rg0 = 128 * s + 8 * rq;
    const float4* Ap = reinterpret_cast<const float4*>(A)
                       + (size_t)rg0 * 128 + 2 * cq;
    const int zb  = rofs(rg0);
    const int c0  = 8 * cq;
    const int lane = tid & 63;
    const int s5 = (lane >> 5) & 1, s4 = (lane >> 4) & 1;
    const int s3 = (lane >> 3) & 1, s2 = (lane >> 2) & 1;

    for (int t = 0; t < NT; ++t) {
        {
            int k1 = tid >> 2, bq = tid & 3;
            float2 o2 = sh.om[k1];
            float2 vv = sh.v[k1];
            int ro0 = rofs(2 * k1);
            float a0[2], a1[2];
            #pragma unroll
            for (int j = 0; j < 2; ++j) {
                float2 xb = sh.x[2 * bq + j];
                float th = o2.x * xb.x + o2.y * xb.y;
                float sn, cs;
                __sincosf(th, &sn, &cs);
                a0[j] = cs * vv.x - sn * vv.y;
                a1[j] = sn * vv.x + cs * vv.y;
            }
            *reinterpret_cast<float2*>(&sh.zxc[ro0 + 2 * bq]) =
                make_float2(a0[0], a0[1]);
            *reinterpret_cast<float2*>(&sh.zxc[ro0 + 12 + 2 * bq]) =
                make_float2(a1[0], a1[1]);
        }
        __syncthreads();

        #pragma unroll
        for (int h = 0; h < 2; ++h) {
            float4 accA[4], accB[4];
            #pragma unroll
            for (int c = 0; c < 4; ++c) {
                accA[c] = make_float4(0.f, 0.f, 0.f, 0.f);
                accB[c] = make_float4(0.f, 0.f, 0.f, 0.f);
            }
            #pragma unroll
            for (int jr = 0; jr < 8; ++jr) {
                float4 a = Ap[(size_t)jr * 128 + h];
                float4 zA = *reinterpret_cast<const float4*>(
                                &sh.zxc[zb + 12 * jr]);
                float4 zB = *reinterpret_cast<const float4*>(
                                &sh.zxc[zb + 12 * jr + 4]);
                float aw[4];
                aw[0] = a.x; aw[1] = a.y; aw[2] = a.z; aw[3] = a.w;
                #pragma unroll
                for (int c = 0; c < 4; ++c) {
                    accA[c].x = fmaf(aw[c], zA.x, accA[c].x);
                    accA[c].y = fmaf(aw[c], zA.y, accA[c].y);
                    accA[c].z = fmaf(aw[c], zA.z, accA[c].z);
                    accA[c].w = fmaf(aw[c], zA.w, accA[c].w);
                    accB[c].x = fmaf(aw[c], zB.x, accB[c].x);
                    accB[c].y = fmaf(aw[c], zB.y, accB[c].y);
                    accB[c].z = fmaf(aw[c], zB.z, accB[c].z);
                    accB[c].w = fmaf(aw[c], zB.w, accB[c].w);
                }
            }

            float4 d0A = make_float4(0,0,0,0), d0B = d0A;
            float4 d1A = d0A, d1B = d0A;
            float4 omv = *reinterpret_cast<const float4*>(
                             &sh.om[4 * cq + 2 * h]);
            #pragma unroll
            for (int pp = 0; pp < 2; ++pp) {
                int rl = rofs(c0 + 4 * h + 2 * pp);
                float4 zl0 = *reinterpret_cast<const float4*>(&sh.zxc[rl]);
                float4 zl1 = *reinterpret_cast<const float4*>(&sh.zxc[rl + 4]);
                float4 zh0 = *reinterpret_cast<const float4*>(&sh.zxc[rl + 12]);
                float4 zh1 = *reinterpret_cast<const float4*>(&sh.zxc[rl + 16]);
                float4 wl = accA[2 * pp], wh = accA[2 * pp + 1];
                float4 gl = accB[2 * pp], gh = accB[2 * pp + 1];
                float4 gA, gB;
                gA.x = fmaf(wh.x, zl0.x, -wl.x * zh0.x);
                gA.y = fmaf(wh.y, zl0.y, -wl.y * zh0.y);
                gA.z = fmaf(wh.z, zl0.z, -wl.z * zh0.z);
                gA.w = fmaf(wh.w, zl0.w, -wl.w * zh0.w);
                gB.x = fmaf(gh.x, zl1.x, -gl.x * zh1.x);
                gB.y = fmaf(gh.y, zl1.y, -gl.y * zh1.y);
                gB.z = fmaf(gh.z, zl1.z, -gl.z * zh1.z);
                gB.w = fmaf(gh.w, zl1.w, -gl.w * zh1.w);
                float ox = pp ? omv.z : omv.x;
                float oy = pp ? omv.w : omv.y;
                d0A.x = fmaf(gA.x, ox, d0A.x); d1A.x = fmaf(gA.x, oy, d1A.x);
                d0A.y = fmaf(gA.y, ox, d0A.y); d1A.y = fmaf(gA.y, oy, d1A.y);
                d0A.z = fmaf(gA.z, ox, d0A.z); d1A.z = fmaf(gA.z, oy, d1A.z);
                d0A.w = fmaf(gA.w, ox, d0A.w); d1A.w = fmaf(gA.w, oy, d1A.w);
                d0B.x = fmaf(gB.x, ox, d0B.x); d1B.x = fmaf(gB.x, oy, d1B.x);
                d0B.y = fmaf(gB.y, ox, d0B.y); d1B.y = fmaf(gB.y, oy, d1B.y);
                d0B.z = fmaf(gB.z, ox, d0B.z); d1B.z = fmaf(gB.z, oy, d1B.z);
                d0B.w = fmaf(gB.w, ox, d0B.w); d1B.w = fmaf(gB.w, oy, d1B.w);
            }

            {
                float r_[16];
                *reinterpret_cast<float4*>(&r_[0])  = d0A;
                *reinterpret_cast<float4*>(&r_[4])  = d0B;
                *reinterpret_cast<float4*>(&r_[8])  = d1A;
                *reinterpret_cast<float4*>(&r_[12]) = d1B;
                #pragma unroll
                for (int k = 0; k < 8; ++k) {
                    float snd = s5 ? r_[k] : r_[k + 8];
                    float rcv = __shfl_xor(snd, 32, 64);
                    r_[k] = (s5 ? r_[k + 8] : r_[k]) + rcv;
                }
                #pragma unroll
                for (int k = 0; k < 4; ++k) {
                    float snd = s4 ? r_[k] : r_[k + 4];
                    float rcv = __shfl_xor(snd, 16, 64);
                    r_[k] = (s4 ? r_[k + 4] : r_[k]) + rcv;
                }
                #pragma unroll
                for (int k = 0; k < 2; ++k) {
                    float snd = s3 ? r_[k] : r_[k + 2];
                    float rcv = __shfl_xor(snd, 8, 64);
                    r_[k] = (s3 ? r_[k + 2] : r_[k]) + rcv;
                }
                {
                    float snd = s2 ? r_[0] : r_[1];
                    float rcv = __shfl_xor(snd, 4, 64);
                    r_[0] = (s2 ? r_[1] : r_[0]) + rcv;
                }
                r_[0] += __shfl_xor(r_[0], 2, 64);
                r_[0] += __shfl_xor(r_[0], 1, 64);
                if ((lane & 3) == 0) {
                    if (h == 0) sh.wred[rq][lane >> 2] = r_[0];
                    else        sh.wred[rq][lane >> 2] += r_[0];
                }
            }
        }
        __syncthreads();

        unsigned long long* pbuf =
            part + ((size_t)(t & 1) * NG + g) * (NS * 16);
        if (tid < 16) {
            float ssum = 0.f;
            #pragma unroll
            for (int w = 0; w < 16; ++w) ssum += sh.wred[w][tid];
            unsigned long long pk =
                (((unsigned long long)(unsigned)(t + 1)) << 32) |
                (unsigned long long)__float_as_uint(ssum);
            __hip_atomic_store(pbuf + s * 16 + tid, pk,
                               __ATOMIC_RELAXED, __HIP_MEMORY_SCOPE_AGENT);
        }
        float val = 0.f;
        if (tid < 64) {
            int sl = tid >> 4, v = tid & 15;
            unsigned long long* addr = pbuf + sl * 16 + v;
            const unsigned long long tgt =
                ((unsigned long long)(unsigned)(t + 1)) << 32;
            unsigned long long pk;
            for (;;) {
                pk = __hip_atomic_load(addr, __ATOMIC_RELAXED,
                                       __HIP_MEMORY_SCOPE_AGENT);
                if (pk >= tgt) break;
                __builtin_amdgcn_s_sleep(1);
            }
            val = __uint_as_float((unsigned)(pk & 0xffffffffull));
            val += __shfl_xor(val, 16, 64);
            val += __shfl_xor(val, 32, 64);
        }
        if (tid < 16) {
            int b = tid & 7, comp = tid >> 3;
            float pi = reinterpret_cast<const float*>(&sh.dpi[b][t])[comp];
            float dtv = fmaf(0.1f, val, pi);
            Sreg += dtv;
            xreg = fminf(fmaxf(xreg + dtv, 0.f), 2.0f);
            reinterpret_cast<float*>(&sh.x[b])[comp] = xreg;
            sh.Sh[t][b][comp] = Sreg;
            sh.xh[t][b][comp] = xreg;
        }
        __syncthreads();
    }

    {
        int th2 = tid >> 9, b = (tid >> 6) & 7, kk = tid & 63;
        float2 zp = reinterpret_cast<const float2*>(z0)
                        [(size_t)(b0 + b) * KP + 64 * s + kk];
        float2 o2 = sh.om[64 * s + kk];
        float2* zout = reinterpret_cast<float2*>(z_seq)
                       + (size_t)(b0 + b) * NT * KP + (64 * s + kk);
        for (int tt2 = th2 * 64, e = th2 * 64 + 64; tt2 < e; ++tt2) {
            float Sx = sh.Sh[tt2][b][0], Sy = sh.Sh[tt2][b][1];
            float th = o2.x * Sx + o2.y * Sy;
            float sn, cs;
            __sincosf(th, &sn, &cs);
            zout[(size_t)tt2 * KP] =
                make_float2(cs * zp.x - sn * zp.y, sn * zp.x + cs * zp.y);
        }
    }
    if (s == 0) {
        int b = tid >> 7, tt3 = tid & 127;
        float2 xv = *reinterpret_cast<const float2*>(&sh.xh[tt3][b][0]);
        reinterpret_cast<float2*>(x_seq)[(size_t)(b0 + b) * NT + tt3] = xv;
    }
}

extern "C" void kernel_launch(void* const* d_in, const int* in_sizes, int n_in,
                              void* d_out, int out_size, void* d_ws, size_t ws_size,
                              hipStream_t stream) {
    (void)in_sizes; (void)n_in; (void)out_size;
    unsigned long long* part = reinterpret_cast<unsigned long long*>(d_ws);
    hipMemsetAsync(d_ws, 0, PART_BYTES, stream);   // zero exchange tags

    const size_t need = PART_BYTES + 2 * A16_BYTES;   // 64K + 1M (as R16)
    if (ws_size >= need) {
        unsigned short* Ah = reinterpret_cast<unsigned short*>(
            reinterpret_cast<char*>(d_ws) + PART_BYTES);
        unsigned short* Al = Ah + (size_t)DD * DD;
        hipLaunchKernelGGL(conv_a, dim3(DD * DD / 512), dim3(512), 0, stream,
                           (const float*)d_in[4], Ah, Al);
        hipLaunchKernelGGL(can_mfma, dim3(NBLK), dim3(1024), 0, stream,
                           (const float*)d_in[0], (const float*)d_in[1],
                           (const float*)d_in[2], (const float*)d_in[3],
                           (const float*)d_in[5], (float*)d_out, part, Ah, Al);
    } else {
        hipLaunchKernelGGL(can_f32, dim3(NBLK), dim3(1024), 0, stream,
                           (const float*)d_in[0], (const float*)d_in[1],
                           (const float*)d_in[2], (const float*)d_in[3],
                           (const float*)d_in[4], (const float*)d_in[5],
                           (float*)d_out, part);
    }
}

// Round 13
// 408.950 us; speedup vs baseline: 1.3831x; 1.3831x over previous
//
#include <hip/hip_runtime.h>
#include <hip/hip_fp16.h>

// CANPathIntegrator — R18: 8-slice x 16-batch geometry (halve L2-A stream,
// kill MFMA mirror waste).
//
// R17 post-mortem: two-set pipeline DOUBLED MFMA work (4 batches in an
// N=16 tile = 4x mirror waste) + doubled barriers/exchange -> 566us
// regression. Reverted. R16 model: 2.97us/step = per-XCD L2 A-stream
// (32 blocks x 256KB = 8MB/step/XCD @ ~4.3TB/s = 1.86us, dominant pipe)
// + serial exchange ~1.1us. This round: NS=8 slices (64 A-rows, 128KB
// f16-split) x NG=32 groups x NB=16 batches:
//   * per-CU A-traffic halves -> 0.93us/step; slice == XCD (bid&7) so
//     each XCD L2 serves one hot 128KB slice.
//   * N=16 MFMA tile holds 16 REAL batches (was 8 + mirror) -> 12
//     MFMA/wave/step (was 24), zero waste.
//   * exchange widens to 8 peers x 32 vals: consume over 256 threads
//     (shfl fold pairs of slices, LDS fold across 4 waves).
// Carried verbatim (R14-R16 verified): f16x2 split-precision MFMA
// (Ah=f16(256A), Al=f16((256A-Ah)*2048); acc1+acc2/2048; all scales fold
// into DXSC=0.1*2^-24; absmax 0.0078125), packed-u64 tag-in-data MALL
// exchange (relaxed, double-buffered by t&1), z_t = R(omega@S_t)z0
// epilogue regeneration. ws guard: need 128KB part + 1MB split-A; falls
// back to the proven R14 f32 kernel (790us) if short.

typedef __attribute__((ext_vector_type(8))) _Float16 half8;
typedef __attribute__((ext_vector_type(4))) float f32x4;

namespace {
constexpr int NT = 128;
constexpr int DD = 512;
constexpr int KP = 256;
constexpr int NS = 8;      // row slices (64 rows each)  [R18]
constexpr int NG = 32;     // batch groups               [R18]
constexpr int NB = 16;     // batches per group          [R18]
constexpr int NBLK = NG * NS;   // 256 = #CUs
constexpr int ZST = 536;   // zh/zl row stride (shorts); 268 dw = 12 mod 32
constexpr size_t PART_BYTES = (size_t)2 * NG * NS * 32 * 8;   // 128 KB
constexpr size_t FB_PART_BYTES = 65536;                       // f32 path
constexpr size_t A16_BYTES  = (size_t)DD * DD * 2;            // 512 KB each
constexpr float LOSC = 1.0f / 2048.0f;
constexpr float DXSC = 0.1f / 16777216.0f;    // 0.1 * 2^-24

__device__ __forceinline__ int rofs(int r) {   // f32-fallback swizzle
    return 12 * r + 4 * ((r >> 3) & 7) + 32 * (r >> 6);
}
}

// ======================= MFMA path (R18 geometry) =====================

struct __align__(16) ShmP {
    unsigned short zh[NB][ZST];   // 17152 B  f16 hi of 256*zx, [b][row]
    unsigned short zl[NB][ZST];   // 17152 B  f16 lo (x2048 residual)
    float2 dpi[NB][NT];           // 16384 B
    float2 om[KP];                //  2048 B
    float2 v[KP];                 //  2048 B  z0hat * 256
    float  wred[16][32];          //  2048 B  per-wave d partials
    float  cred[4][32];           //   512 B  consume fold across waves
    float  Sh[NT][NB][2];         // 16384 B
    float  xh[NT][NB][2];         // 16384 B
    float2 x[NB];                 //   128 B
    float  nred[16];              //    64 B
};   // ~90.3 KB -> 1 block/CU (spin-safe), fits 160KB

__global__ __launch_bounds__(512) void conv_a(
    const float* __restrict__ A,
    unsigned short* __restrict__ Ah, unsigned short* __restrict__ Al)
{
    int i = blockIdx.x * 512 + threadIdx.x;
    float a = A[i] * 256.0f;
    __half h = __float2half(a);
    float r = (a - __half2float(h)) * 2048.0f;
    Ah[i] = __half_as_ushort(h);
    Al[i] = __half_as_ushort(__float2half(r));
}

__attribute__((amdgpu_flat_work_group_size(1024, 1024),
               amdgpu_waves_per_eu(4, 4)))
__global__ void can_mfma(
    const float* __restrict__ dx_pi, const float* __restrict__ z0,
    const float* __restrict__ x0, const float* __restrict__ omega,
    const float* __restrict__ z0b, float* __restrict__ d_out,
    unsigned long long* __restrict__ part,
    const unsigned short* __restrict__ Ah,
    const unsigned short* __restrict__ Al)
{
    __shared__ ShmP sh;
    const int tid = threadIdx.x;
    const int g   = blockIdx.x >> 3;    // batch group
    const int s   = blockIdx.x & 7;     // slice: rows 64s..64s+63 (== XCD)
    const int b0  = NB * g;

    float* z_seq = d_out;
    float* x_seq = d_out + (size_t)512 * NT * DD;

    // ---- preloads ----
    #pragma unroll
    for (int it = 0; it < 2; ++it) {
        int idx = tid + (it << 10);     // 2048 float2 of dpi
        int bb = idx >> 7, tt = idx & 127;
        sh.dpi[bb][tt] =
            reinterpret_cast<const float2*>(dx_pi)[(size_t)(b0 + bb) * NT + tt];
    }
    if (tid < KP) sh.om[tid] = reinterpret_cast<const float2*>(omega)[tid];

    // ||z0_base|| -> normalize once; v = z0hat * 256
    float sq = 0.f;
    if (tid < DD) { float f = z0b[tid]; sq = f * f; }
    #pragma unroll
    for (int o = 1; o < 64; o <<= 1) sq += __shfl_xor(sq, o, 64);
    if ((tid & 63) == 0) sh.nred[tid >> 6] = sq;
    __syncthreads();
    float nsq = 0.f;
    #pragma unroll
    for (int w2 = 0; w2 < 16; ++w2) nsq += sh.nred[w2];
    const float zs = 256.0f / (sqrtf(nsq) + 1e-5f);
    if (tid < KP) {
        float2 vv = reinterpret_cast<const float2*>(z0b)[tid];
        sh.v[tid] = make_float2(vv.x * zs, vv.y * zs);
    }

    // owner state: tid<32 owns (b = tid&15, comp = tid>>4)
    float xreg = 0.f, Sreg = 0.f;
    if (tid < 32) {
        int b = tid & 15, comp = tid >> 4;
        xreg = x0[(size_t)(b0 + b) * 2 + comp];
        reinterpret_cast<float*>(&sh.x[b])[comp] = xreg;
    }
    __syncthreads();

    // MFMA roles: wave w owns M-tiles 2w, 2w+1 (cols 32w..32w+31)
    const int w   = tid >> 6;
    const int l   = tid & 63;
    const int cB  = l & 15;            // A-frag m (within tile); C col = batch
    const int kg  = l >> 4;            // k-chunk 0..3 (8 rows each)
    const int bB  = l & 15;            // batch for B-frag / contract
    const int mt0 = 2 * w;
    const unsigned short* AhP =
        Ah + (size_t)(16 * mt0 + cB) * DD + (64 * s + 8 * kg);
    const unsigned short* AlP =
        Al + (size_t)(16 * mt0 + cB) * DD + (64 * s + 8 * kg);

    for (int t = 0; t < NT; ++t) {
        // ---- P1: zx rows 2k1,2k1+1 for batches 4bq..4bq+3, f16 split ----
        {
            int k1 = tid & 255, bq = tid >> 8;   // bq in 0..3
            float2 o2 = sh.om[k1];
            float2 vv = sh.v[k1];
            #pragma unroll
            for (int j = 0; j < 4; ++j) {
                int b = 4 * bq + j;
                float2 xb = sh.x[b];
                float th = o2.x * xb.x + o2.y * xb.y;
                float sn, cs;
                __sincosf(th, &sn, &cs);
                float za  = cs * vv.x - sn * vv.y;
                float zb2 = sn * vv.x + cs * vv.y;
                __half h0 = __float2half(za);
                __half h1 = __float2half(zb2);
                unsigned l0 = __half_as_ushort(
                    __float2half((za - __half2float(h0)) * 2048.f));
                unsigned l1 = __half_as_ushort(
                    __float2half((zb2 - __half2float(h1)) * 2048.f));
                *reinterpret_cast<unsigned*>(&sh.zh[b][2 * k1]) =
                    (unsigned)__half_as_ushort(h0) |
                    ((unsigned)__half_as_ushort(h1) << 16);
                *reinterpret_cast<unsigned*>(&sh.zl[b][2 * k1]) =
                    l0 | (l1 << 16);
            }
        }
        __syncthreads();

        // ---- P2: split-precision MFMA; K=64 (2 chunks), N=16 batches ----
        f32x4 ac1[2] = {{0.f,0.f,0.f,0.f},{0.f,0.f,0.f,0.f}};
        f32x4 ac2[2] = {{0.f,0.f,0.f,0.f},{0.f,0.f,0.f,0.f}};
        #pragma unroll
        for (int kt = 0; kt < 2; ++kt) {
            int rg = 64 * s + 32 * kt + 8 * kg;
            half8 bh = *reinterpret_cast<const half8*>(&sh.zh[bB][rg]);
            half8 bl = *reinterpret_cast<const half8*>(&sh.zl[bB][rg]);
            #pragma unroll
            for (int mi = 0; mi < 2; ++mi) {
                half8 ah = *reinterpret_cast<const half8*>(
                               AhP + (size_t)mi * 16 * DD + 32 * kt);
                half8 al = *reinterpret_cast<const half8*>(
                               AlP + (size_t)mi * 16 * DD + 32 * kt);
                ac1[mi] = __builtin_amdgcn_mfma_f32_16x16x32_f16(
                              ah, bh, ac1[mi], 0, 0, 0);
                ac2[mi] = __builtin_amdgcn_mfma_f32_16x16x32_f16(
                              al, bh, ac2[mi], 0, 0, 0);
                ac2[mi] = __builtin_amdgcn_mfma_f32_16x16x32_f16(
                              ah, bl, ac2[mi], 0, 0, 0);
            }
        }

        // ---- contract in-register (linear in w): lane has w for its
        //      batch bB at cols cb..cb+3 (two aligned pairs) ----
        float d0 = 0.f, d1 = 0.f;
        #pragma unroll
        for (int mi = 0; mi < 2; ++mi) {
            int cb = 16 * (mt0 + mi) + 4 * kg;
            float wv0 = fmaf(ac2[mi][0], LOSC, ac1[mi][0]);
            float wv1 = fmaf(ac2[mi][1], LOSC, ac1[mi][1]);
            float wv2 = fmaf(ac2[mi][2], LOSC, ac1[mi][2]);
            float wv3 = fmaf(ac2[mi][3], LOSC, ac1[mi][3]);
            uint2 zhp = *reinterpret_cast<const uint2*>(&sh.zh[bB][cb]);
            uint2 zlp = *reinterpret_cast<const uint2*>(&sh.zl[bB][cb]);
            float z0v = fmaf(__half2float(__ushort_as_half(
                                 (unsigned short)(zlp.x & 0xffff))), LOSC,
                             __half2float(__ushort_as_half(
                                 (unsigned short)(zhp.x & 0xffff))));
            float z1v = fmaf(__half2float(__ushort_as_half(
                                 (unsigned short)(zlp.x >> 16))), LOSC,
                             __half2float(__ushort_as_half(
                                 (unsigned short)(zhp.x >> 16))));
            float z2v = fmaf(__half2float(__ushort_as_half(
                                 (unsigned short)(zlp.y & 0xffff))), LOSC,
                             __half2float(__ushort_as_half(
                                 (unsigned short)(zhp.y & 0xffff))));
            float z3v = fmaf(__half2float(__ushort_as_half(
                                 (unsigned short)(zlp.y >> 16))), LOSC,
                             __half2float(__ushort_as_half(
                                 (unsigned short)(zhp.y >> 16))));
            float g0 = fmaf(wv1, z0v, -wv0 * z1v);
            float g1 = fmaf(wv3, z2v, -wv2 * z3v);
            float4 omq = *reinterpret_cast<const float4*>(&sh.om[cb >> 1]);
            d0 = fmaf(g0, omq.x, d0); d1 = fmaf(g0, omq.y, d1);
            d0 = fmaf(g1, omq.z, d0); d1 = fmaf(g1, omq.w, d1);
        }

        // reduce over kg variants {l, l^16, l^32, l^48} (same batch)
        d0 += __shfl_xor(d0, 16, 64);  d0 += __shfl_xor(d0, 32, 64);
        d1 += __shfl_xor(d1, 16, 64);  d1 += __shfl_xor(d1, 32, 64);
        if (l < 16) {                   // value v: b for d0, 16+b for d1
            sh.wred[w][l]      = d0;
            sh.wred[w][l + 16] = d1;
        }
        __syncthreads();

        // ---- publish: fold 16 waves; 32 packed (tag|value) u64 stores ----
        unsigned long long* pbuf =
            part + ((size_t)(t & 1) * NG + g) * (NS * 32);
        if (tid < 32) {
            float ssum = 0.f;
            #pragma unroll
            for (int w2 = 0; w2 < 16; ++w2) ssum += sh.wred[w2][tid];
            unsigned long long pk =
                (((unsigned long long)(unsigned)(t + 1)) << 32) |
                (unsigned long long)__float_as_uint(ssum);
            __hip_atomic_store(pbuf + s * 32 + tid, pk,
                               __ATOMIC_RELAXED, __HIP_MEMORY_SCOPE_AGENT);
        }

        // ---- consume: 256 threads poll (sl = tid>>5, v = tid&31) ----
        if (tid < 256) {
            int sl = tid >> 5, v = tid & 31;
            unsigned long long* addr = pbuf + sl * 32 + v;
            const unsigned long long tgt =
                ((unsigned long long)(unsigned)(t + 1)) << 32;
            unsigned long long pk;
            for (;;) {
                pk = __hip_atomic_load(addr, __ATOMIC_RELAXED,
                                       __HIP_MEMORY_SCOPE_AGENT);
                if (pk >= tgt) break;
                __builtin_amdgcn_s_sleep(1);
            }
            float val = __uint_as_float((unsigned)(pk & 0xffffffffull));
            val += __shfl_xor(val, 32, 64);    // fold slice pairs in-wave
            if (l < 32) sh.cred[w][v] = val;   // waves 0..3
        }
        __syncthreads();

        // ---- owner: sum 4 wave-folds -> dx_total; update x, S ----
        if (tid < 32) {
            int b = tid & 15, comp = tid >> 4;
            float val = sh.cred[0][tid] + sh.cred[1][tid]
                      + sh.cred[2][tid] + sh.cred[3][tid];
            float pi = reinterpret_cast<const float*>(&sh.dpi[b][t])[comp];
            float dtv = fmaf(DXSC, val, pi);
            Sreg += dtv;                                  // unclipped cumsum
            xreg = fminf(fmaxf(xreg + dtv, 0.f), 2.0f);   // clipped x
            reinterpret_cast<float*>(&sh.x[b])[comp] = xreg;
            sh.Sh[t][b][comp] = Sreg;
            sh.xh[t][b][comp] = xreg;
        }
        __syncthreads();
    }

    // ---- epilogue: z_seq[b][t][slice cols] = R(omega@S_t) z0[b] ----
    {
        int th2 = tid >> 9, b = (tid >> 5) & 15, kk = tid & 31;
        float2 zp = reinterpret_cast<const float2*>(z0)
                        [(size_t)(b0 + b) * KP + 32 * s + kk];
        float2 o2 = sh.om[32 * s + kk];
        float2* zout = reinterpret_cast<float2*>(z_seq)
                       + (size_t)(b0 + b) * NT * KP + (32 * s + kk);
        for (int tt2 = th2 * 64, e = th2 * 64 + 64; tt2 < e; ++tt2) {
            float Sx = sh.Sh[tt2][b][0], Sy = sh.Sh[tt2][b][1];
            float th = o2.x * Sx + o2.y * Sy;
            float sn, cs;
            __sincosf(th, &sn, &cs);
            zout[(size_t)tt2 * KP] =
                make_float2(cs * zp.x - sn * zp.y, sn * zp.x + cs * zp.y);
        }
    }
    if (s == 0) {   // x_seq from LDS history: thread -> (b, 2 steps)
        int b = tid >> 6, tp = tid & 63;        // t = 2tp, 2tp+1
        float2 x0v = *reinterpret_cast<const float2*>(&sh.xh[2 * tp][b][0]);
        float2 x1v = *reinterpret_cast<const float2*>(&sh.xh[2 * tp + 1][b][0]);
        *reinterpret_cast<float4*>(
            &x_seq[((size_t)(b0 + b) * NT + 2 * tp) * 2]) =
            make_float4(x0v.x, x0v.y, x1v.x, x1v.y);
    }
}

// =================== f32 fallback path (R14, proven) ===================

namespace {
constexpr int FNS = 4;
constexpr int FNG = 64;
constexpr int FNB = 8;
}

struct __align__(16) ShmF {
    float  zxc[6400];
    float2 dpi[FNB][NT];
    float2 om[KP];
    float2 v[KP];
    float  wred[16][16];
    float  Sh[NT][FNB][2];
    float  xh[NT][FNB][2];
    float2 x[FNB];
    float  nred[16];
    float  pad[7168];
};

__attribute__((amdgpu_flat_work_group_size(1024, 1024),
               amdgpu_waves_per_eu(4, 4)))
__global__ void can_f32(
    const float* __restrict__ dx_pi, const float* __restrict__ z0,
    const float* __restrict__ x0, const float* __restrict__ omega,
    const float* __restrict__ A, const float* __restrict__ z0b,
    float* __restrict__ d_out,
    unsigned long long* __restrict__ part)
{
    __shared__ ShmF sh;
    const int tid = threadIdx.x;
    const int g   = blockIdx.x >> 2;
    const int s   = blockIdx.x & 3;
    const int b0  = FNB * g;

    float* z_seq = d_out;
    float* x_seq = d_out + (size_t)512 * NT * DD;

    if (dx_pi == nullptr) ((volatile float*)sh.pad)[0] = 1.f;

    {
        int bb = tid >> 7, tt = tid & 127;
        sh.dpi[bb][tt] =
            reinterpret_cast<const float2*>(dx_pi)[(size_t)(b0 + bb) * NT + tt];
    }
    if (tid < KP) sh.om[tid] = reinterpret_cast<const float2*>(omega)[tid];

    float sq = 0.f;
    if (tid < DD) { float f = z0b[tid]; sq = f * f; }
    #pragma unroll
    for (int o = 1; o < 64; o <<= 1) sq += __shfl_xor(sq, o, 64);
    if ((tid & 63) == 0) sh.nred[tid >> 6] = sq;
    __syncthreads();
    float nsq = 0.f;
    #pragma unroll
    for (int w = 0; w < 16; ++w) nsq += sh.nred[w];
    const float zinv = 1.0f / (sqrtf(nsq) + 1e-5f);
    if (tid < KP) {
        float2 vv = reinterpret_cast<const float2*>(z0b)[tid];
        sh.v[tid] = make_float2(vv.x * zinv, vv.y * zinv);
    }

    float xreg = 0.f, Sreg = 0.f;
    if (tid < 16) {
        int b = tid & 7, comp = tid >> 3;
        xreg = x0[(size_t)(b0 + b) * 2 + comp];
        reinterpret_cast<float*>(&sh.x[b])[comp] = xreg;
    }
    __syncthreads();

    const int rq  = tid >> 6;
    const int cq  = tid & 63;
    const int rg0 = 128 * s + 8 * rq;
    const float4* Ap = reinterpret_cast<const float4*>(A)
                       + (size_t)rg0 * 128 + 2 * cq;
    const int zb  = rofs(rg0);
    const int c0  = 8 * cq;
    const int lane = tid & 63;
    const int s5 = (lane >> 5) & 1, s4 = (lane >> 4) & 1;
    const int s3 = (lane >> 3) & 1, s2 = (lane >> 2) & 1;

    for (int t = 0; t < NT; ++t) {
        {
            int k1 = tid >> 2, bq = tid & 3;
            float2 o2 = sh.om[k1];
            float2 vv = sh.v[k1];
            int ro0 = rofs(2 * k1);
            float a0[2], a1[2];
            #pragma unroll
            for (int j = 0; j < 2; ++j) {
                float2 xb = sh.x[2 * bq + j];
                float th = o2.x * xb.x + o2.y * xb.y;
                float sn, cs;
                __sincosf(th, &sn, &cs);
                a0[j] = cs * vv.x - sn * vv.y;
                a1[j] = sn * vv.x + cs * vv.y;
            }
            *reinterpret_cast<float2*>(&sh.zxc[ro0 + 2 * bq]) =
                make_float2(a0[0], a0[1]);
            *reinterpret_cast<float2*>(&sh.zxc[ro0 + 12 + 2 * bq]) =
                make_float2(a1[0], a1[1]);
        }
        __syncthreads();

        #pragma unroll
        for (int h = 0; h < 2; ++h) {
            float4 accA[4], accB[4];
            #pragma unroll
            for (int c = 0; c < 4; ++c) {
                accA[c] = make_float4(0.f, 0.f, 0.f, 0.f);
                accB[c] = make_float4(0.f, 0.f, 0.f, 0.f);
            }
            #pragma unroll
            for (int jr = 0; jr < 8; ++jr) {
                float4 a = Ap[(size_t)jr * 128 + h];
                float4 zA = *reinterpret_cast<const float4*>(
                                &sh.zxc[zb + 12 * jr]);
                float4 zB = *reinterpret_cast<const float4*>(
                                &sh.zxc[zb + 12 * jr + 4]);
                float aw[4];
                aw[0] = a.x; aw[1] = a.y; aw[2] = a.z; aw[3] = a.w;
                #pragma unroll
                for (int c = 0; c < 4; ++c) {
                    accA[c].x = fmaf(aw[c], zA.x, accA[c].x);
                    accA[c].y = fmaf(aw[c], zA.y, accA[c].y);
                    accA[c].z = fmaf(aw[c], zA.z, accA[c].z);
                    accA[c].w = fmaf(aw[c], zA.w, accA[c].w);
                    accB[c].x = fmaf(aw[c], zB.x, accB[c].x);
                    accB[c].y = fmaf(aw[c], zB.y, accB[c].y);
                    accB[c].z = fmaf(aw[c], zB.z, accB[c].z);
                    accB[c].w = fmaf(aw[c], zB.w, accB[c].w);
                }
            }

            float4 d0A = make_float4(0,0,0,0), d0B = d0A;
            float4 d1A = d0A, d1B = d0A;
            float4 omv = *reinterpret_cast<const float4*>(
                             &sh.om[4 * cq + 2 * h]);
            #pragma unroll
            for (int pp = 0; pp < 2; ++pp) {
                int rl = rofs(c0 + 4 * h + 2 * pp);
                float4 zl0 = *reinterpret_cast<const float4*>(&sh.zxc[rl]);
                float4 zl1 = *reinterpret_cast<const float4*>(&sh.zxc[rl + 4]);
                float4 zh0 = *reinterpret_cast<const float4*>(&sh.zxc[rl + 12]);
                float4 zh1 = *reinterpret_cast<const float4*>(&sh.zxc[rl + 16]);
                float4 wl = accA[2 * pp], wh = accA[2 * pp + 1];
                float4 gl = accB[2 * pp], gh = accB[2 * pp + 1];
                float4 gA, gB;
                gA.x = fmaf(wh.x, zl0.x, -wl.x * zh0.x);
                gA.y = fmaf(wh.y, zl0.y, -wl.y * zh0.y);
                gA.z = fmaf(wh.z, zl0.z, -wl.z * zh0.z);
                gA.w = fmaf(wh.w, zl0.w, -wl.w * zh0.w);
                gB.x = fmaf(gh.x, zl1.x, -gl.x * zh1.x);
                gB.y = fmaf(gh.y, zl1.y, -gl.y * zh1.y);
                gB.z = fmaf(gh.z, zl1.z, -gl.z * zh1.z);
                gB.w = fmaf(gh.w, zl1.w, -gl.w * zh1.w);
                float ox = pp ? omv.z : omv.x;
                float oy = pp ? omv.w : omv.y;
                d0A.x = fmaf(gA.x, ox, d0A.x); d1A.x = fmaf(gA.x, oy, d1A.x);
                d0A.y = fmaf(gA.y, ox, d0A.y); d1A.y = fmaf(gA.y, oy, d1A.y);
                d0A.z = fmaf(gA.z, ox, d0A.z); d1A.z = fmaf(gA.z, oy, d1A.z);
                d0A.w = fmaf(gA.w, ox, d0A.w); d1A.w = fmaf(gA.w, oy, d1A.w);
                d0B.x = fmaf(gB.x, ox, d0B.x); d1B.x = fmaf(gB.x, oy, d1B.x);
                d0B.y = fmaf(gB.y, ox, d0B.y); d1B.y = fmaf(gB.y, oy, d1B.y);
                d0B.z = fmaf(gB.z, ox, d0B.z); d1B.z = fmaf(gB.z, oy, d1B.z);
                d0B.w = fmaf(gB.w, ox, d0B.w); d1B.w = fmaf(gB.w, oy, d1B.w);
            }

            {
                float r_[16];
                *reinterpret_cast<float4*>(&r_[0])  = d0A;
                *reinterpret_cast<float4*>(&r_[4])  = d0B;
                *reinterpret_cast<float4*>(&r_[8])  = d1A;
                *reinterpret_cast<float4*>(&r_[12]) = d1B;
                #pragma unroll
                for (int k = 0; k < 8; ++k) {
                    float snd = s5 ? r_[k] : r_[k + 8];
                    float rcv = __shfl_xor(snd, 32, 64);
                    r_[k] = (s5 ? r_[k + 8] : r_[k]) + rcv;
                }
                #pragma unroll
                for (int k = 0; k < 4; ++k) {
                    float snd = s4 ? r_[k] : r_[k + 4];
                    float rcv = __shfl_xor(snd, 16, 64);
                    r_[k] = (s4 ? r_[k + 4] : r_[k]) + rcv;
                }
                #pragma unroll
                for (int k = 0; k < 2; ++k) {
                    float snd = s3 ? r_[k] : r_[k + 2];
                    float rcv = __shfl_xor(snd, 8, 64);
                    r_[k] = (s3 ? r_[k + 2] : r_[k]) + rcv;
                }
                {
                    float snd = s2 ? r_[0] : r_[1];
                    float rcv = __shfl_xor(snd, 4, 64);
                    r_[0] = (s2 ? r_[1] : r_[0]) + rcv;
                }
                r_[0] += __shfl_xor(r_[0], 2, 64);
                r_[0] += __shfl_xor(r_[0], 1, 64);
                if ((lane & 3) == 0) {
                    if (h == 0) sh.wred[rq][lane >> 2] = r_[0];
                    else        sh.wred[rq][lane >> 2] += r_[0];
                }
            }
        }
        __syncthreads();

        unsigned long long* pbuf =
            part + ((size_t)(t & 1) * FNG + g) * (FNS * 16);
        if (tid < 16) {
            float ssum = 0.f;
            #pragma unroll
            for (int w = 0; w < 16; ++w) ssum += sh.wred[w][tid];
            unsigned long long pk =
                (((unsigned long long)(unsigned)(t + 1)) << 32) |
                (unsigned long long)__float_as_uint(ssum);
            __hip_atomic_store(pbuf + s * 16 + tid, pk,
                               __ATOMIC_RELAXED, __HIP_MEMORY_SCOPE_AGENT);
        }
        float val = 0.f;
        if (tid < 64) {
            int sl = tid >> 4, v = tid & 15;
            unsigned long long* addr = pbuf + sl * 16 + v;
            const unsigned long long tgt =
                ((unsigned long long)(unsigned)(t + 1)) << 32;
            unsigned long long pk;
            for (;;) {
                pk = __hip_atomic_load(addr, __ATOMIC_RELAXED,
                                       __HIP_MEMORY_SCOPE_AGENT);
                if (pk >= tgt) break;
                __builtin_amdgcn_s_sleep(1);
            }
            val = __uint_as_float((unsigned)(pk & 0xffffffffull));
            val += __shfl_xor(val, 16, 64);
            val += __shfl_xor(val, 32, 64);
        }
        if (tid < 16) {
            int b = tid & 7, comp = tid >> 3;
            float pi = reinterpret_cast<const float*>(&sh.dpi[b][t])[comp];
            float dtv = fmaf(0.1f, val, pi);
            Sreg += dtv;
            xreg = fminf(fmaxf(xreg + dtv, 0.f), 2.0f);
            reinterpret_cast<float*>(&sh.x[b])[comp] = xreg;
            sh.Sh[t][b][comp] = Sreg;
            sh.xh[t][b][comp] = xreg;
        }
        __syncthreads();
    }

    {
        int th2 = tid >> 9, b = (tid >> 6) & 7, kk = tid & 63;
        float2 zp = reinterpret_cast<const float2*>(z0)
                        [(size_t)(b0 + b) * KP + 64 * s + kk];
        float2 o2 = sh.om[64 * s + kk];
        float2* zout = reinterpret_cast<float2*>(z_seq)
                       + (size_t)(b0 + b) * NT * KP + (64 * s + kk);
        for (int tt2 = th2 * 64, e = th2 * 64 + 64; tt2 < e; ++tt2) {
            float Sx = sh.Sh[tt2][b][0], Sy = sh.Sh[tt2][b][1];
            float th = o2.x * Sx + o2.y * Sy;
            float sn, cs;
            __sincosf(th, &sn, &cs);
            zout[(size_t)tt2 * KP] =
                make_float2(cs * zp.x - sn * zp.y, sn * zp.x + cs * zp.y);
        }
    }
    if (s == 0) {
        int b = tid >> 7, tt3 = tid & 127;
        float2 xv = *reinterpret_cast<const float2*>(&sh.xh[tt3][b][0]);
        reinterpret_cast<float2*>(x_seq)[(size_t)(b0 + b) * NT + tt3] = xv;
    }
}

extern "C" void kernel_launch(void* const* d_in, const int* in_sizes, int n_in,
                              void* d_out, int out_size, void* d_ws, size_t ws_size,
                              hipStream_t stream) {
    (void)in_sizes; (void)n_in; (void)out_size;
    unsigned long long* part = reinterpret_cast<unsigned long long*>(d_ws);

    const size_t need = PART_BYTES + 2 * A16_BYTES;   // 128K + 1M
    if (ws_size >= need) {
        hipMemsetAsync(d_ws, 0, PART_BYTES, stream);
        unsigned short* Ah = reinterpret_cast<unsigned short*>(
            reinterpret_cast<char*>(d_ws) + PART_BYTES);
        unsigned short* Al = Ah + (size_t)DD * DD;
        hipLaunchKernelGGL(conv_a, dim3(DD * DD / 512), dim3(512), 0, stream,
                           (const float*)d_in[4], Ah, Al);
        hipLaunchKernelGGL(can_mfma, dim3(NBLK), dim3(1024), 0, stream,
                           (const float*)d_in[0], (const float*)d_in[1],
                           (const float*)d_in[2], (const float*)d_in[3],
                           (const float*)d_in[5], (float*)d_out, part, Ah, Al);
    } else {
        hipMemsetAsync(d_ws, 0, FB_PART_BYTES, stream);
        hipLaunchKernelGGL(can_f32, dim3(NBLK), dim3(1024), 0, stream,
                           (const float*)d_in[0], (const float*)d_in[1],
                           (const float*)d_in[2], (const float*)d_in[3],
                           (const float*)d_in[4], (const float*)d_in[5],
                           (float*)d_out, part);
    }
}

// Round 14
// 386.432 us; speedup vs baseline: 1.4637x; 1.0583x over previous
//
#include <hip/hip_runtime.h>
#include <hip/hip_fp16.h>

// CANPathIntegrator — R19: R16 + persistent A-register fragments.
//
// R18 post-mortem: halving the L2-A stream worked (MfmaUtil 21->10 with
// half the MFMAs) but the 8-peer exchange widening ate the gain (FETCH
// 11->36MB from 256-thread polling, +2 barriers) -> 409us vs R16's 380.
// Reverted to R16's NS=4 narrow exchange. This round removes the L2-A
// term (1.86us/step, the largest pipe term) WITHOUT touching the
// exchange: A is TIME-INVARIANT, so each wave's MFMA A-fragments are
// identical every step. Load each lane's 16 half8 fragments (ahr/alr,
// 4 k-chunks x 2 M-tiles = 64 VGPRs) ONCE in the prologue; the step loop
// then has zero A-memory traffic. R18's VGPR_Count=52 proved the
// allocator is demand-driven under amdgpu_waves_per_eu(4,4) (the old
// 64-cap was the 8-wave default target of R9/R10's launch_bounds);
// peak live ~115 fits the 128 budget at 4 waves/EU.
// Failure signature if the cap is hard: VGPR=64 + FETCH in GBs + ~2ms
// (spill) -> next round would put Ah in LDS instead.
//
// Carried verbatim (R14-R16 verified, absmax 0.0078125):
//   * f16x2 split-precision MFMA: Ah=f16(256A), Al=f16((256A-Ah)*2048);
//     acc1 += Ah*zh, acc2 += Al*zh + Ah*zl; w' = acc1 + acc2/2048;
//     all scales fold into DXSC = 0.1*2^-24 at the owner update.
//   * packed-u64 tag-in-data MALL exchange (relaxed, dbuf by t&1).
//   * z_t = R(omega@S_t) z0 epilogue regeneration (rotations commute).
//   * ws guard -> proven R14 f32 kernel (790us) if workspace too small.

typedef __attribute__((ext_vector_type(8))) _Float16 half8;
typedef __attribute__((ext_vector_type(4))) float f32x4;

namespace {
constexpr int NT = 128;
constexpr int DD = 512;
constexpr int KP = 256;
constexpr int NS = 4;      // row slices (128 rows each)
constexpr int NG = 64;     // batch groups
constexpr int NB = 8;      // batches per group
constexpr int NBLK = NG * NS;   // 256 = #CUs
constexpr int ZST = 536;   // zh/zl row stride (shorts)
constexpr size_t PART_BYTES = (size_t)2 * NG * NS * 16 * 8;   // 64 KB
constexpr size_t A16_BYTES  = (size_t)DD * DD * 2;            // 512 KB each
constexpr float LOSC = 1.0f / 2048.0f;
constexpr float DXSC = 0.1f / 16777216.0f;    // 0.1 * 2^-24

__device__ __forceinline__ int rofs(int r) {   // f32-fallback swizzle
    return 12 * r + 4 * ((r >> 3) & 7) + 32 * (r >> 6);
}
}

// ======================= MFMA path (R19) ==============================

struct __align__(16) ShmM {
    unsigned short zh[NB][ZST];   //  8576 B  f16 hi of 256*zx, [b][r]
    unsigned short zl[NB][ZST];   //  8576 B  f16 lo (x2048 residual)
    float2 dpi[NB][NT];           //  8192 B
    float2 om[KP];                //  2048 B
    float2 v[KP];                 //  2048 B  z0hat * 256
    float  wred[16][16];          //  1024 B
    float  Sh[NT][NB][2];         //  8192 B
    float  xh[NT][NB][2];         //  8192 B
    float2 x[NB];                 //    64 B
    float  nred[16];              //    64 B
    float  pad[8900];             // 35600 B -> ~82.5 KB total: 1 block/CU
};

__global__ __launch_bounds__(512) void conv_a(
    const float* __restrict__ A,
    unsigned short* __restrict__ Ah, unsigned short* __restrict__ Al)
{
    int i = blockIdx.x * 512 + threadIdx.x;
    float a = A[i] * 256.0f;
    __half h = __float2half(a);
    float r = (a - __half2float(h)) * 2048.0f;
    Ah[i] = __half_as_ushort(h);
    Al[i] = __half_as_ushort(__float2half(r));
}

__attribute__((amdgpu_flat_work_group_size(1024, 1024),
               amdgpu_waves_per_eu(4, 4)))
__global__ void can_mfma(
    const float* __restrict__ dx_pi, const float* __restrict__ z0,
    const float* __restrict__ x0, const float* __restrict__ omega,
    const float* __restrict__ z0b, float* __restrict__ d_out,
    unsigned long long* __restrict__ part,
    const unsigned short* __restrict__ Ah,
    const unsigned short* __restrict__ Al)
{
    __shared__ ShmM sh;
    const int tid = threadIdx.x;
    const int g   = blockIdx.x >> 2;
    const int s   = blockIdx.x & 3;
    const int b0  = NB * g;

    float* z_seq = d_out;
    float* x_seq = d_out + (size_t)512 * NT * DD;

    if (dx_pi == nullptr) ((volatile float*)sh.pad)[0] = 1.f;

    {
        int bb = tid >> 7, tt = tid & 127;
        sh.dpi[bb][tt] =
            reinterpret_cast<const float2*>(dx_pi)[(size_t)(b0 + bb) * NT + tt];
    }
    if (tid < KP) sh.om[tid] = reinterpret_cast<const float2*>(omega)[tid];

    float sq = 0.f;
    if (tid < DD) { float f = z0b[tid]; sq = f * f; }
    #pragma unroll
    for (int o = 1; o < 64; o <<= 1) sq += __shfl_xor(sq, o, 64);
    if ((tid & 63) == 0) sh.nred[tid >> 6] = sq;
    __syncthreads();
    float nsq = 0.f;
    #pragma unroll
    for (int w2 = 0; w2 < 16; ++w2) nsq += sh.nred[w2];
    const float zs = 256.0f / (sqrtf(nsq) + 1e-5f);
    if (tid < KP) {
        float2 vv = reinterpret_cast<const float2*>(z0b)[tid];
        sh.v[tid] = make_float2(vv.x * zs, vv.y * zs);
    }

    float xreg = 0.f, Sreg = 0.f;
    if (tid < 16) {
        int b = tid & 7, comp = tid >> 3;
        xreg = x0[(size_t)(b0 + b) * 2 + comp];
        reinterpret_cast<float*>(&sh.x[b])[comp] = xreg;
    }
    __syncthreads();

    // MFMA roles
    const int w   = tid >> 6;          // wave -> M-tiles 2w, 2w+1
    const int l   = tid & 63;
    const int cB  = l & 15;            // A-frag m / C col
    const int kg  = l >> 4;            // k-chunk 0..3
    const int bB  = l & 7;             // batch (mirrored x2)
    const int mt0 = 2 * w;
    const unsigned short* AhP =
        Ah + (size_t)(16 * mt0 + cB) * DD + (128 * s + 8 * kg);
    const unsigned short* AlP =
        Al + (size_t)(16 * mt0 + cB) * DD + (128 * s + 8 * kg);

    // ---- R19: load persistent A fragments ONCE (A is time-invariant).
    //      16 x half8 = 64 VGPRs/lane; the step loop has zero A traffic.
    half8 ahr[4][2], alr[4][2];
    #pragma unroll
    for (int kt = 0; kt < 4; ++kt) {
        #pragma unroll
        for (int mi = 0; mi < 2; ++mi) {
            ahr[kt][mi] = *reinterpret_cast<const half8*>(
                              AhP + (size_t)mi * 16 * DD + 32 * kt);
            alr[kt][mi] = *reinterpret_cast<const half8*>(
                              AlP + (size_t)mi * 16 * DD + 32 * kt);
        }
    }

    for (int t = 0; t < NT; ++t) {
        // P1: f16-split zx
        {
            int k1 = tid >> 2, bq = tid & 3;
            float2 o2 = sh.om[k1];
            float2 vv = sh.v[k1];
            #pragma unroll
            for (int j = 0; j < 2; ++j) {
                int b = 2 * bq + j;
                float2 xb = sh.x[b];
                float th = o2.x * xb.x + o2.y * xb.y;
                float sn, cs;
                __sincosf(th, &sn, &cs);
                float za  = cs * vv.x - sn * vv.y;
                float zb2 = sn * vv.x + cs * vv.y;
                __half h0 = __float2half(za);
                __half h1 = __float2half(zb2);
                unsigned l0 = __half_as_ushort(
                    __float2half((za - __half2float(h0)) * 2048.f));
                unsigned l1 = __half_as_ushort(
                    __float2half((zb2 - __half2float(h1)) * 2048.f));
                *reinterpret_cast<unsigned*>(&sh.zh[b][2 * k1]) =
                    (unsigned)__half_as_ushort(h0) |
                    ((unsigned)__half_as_ushort(h1) << 16);
                *reinterpret_cast<unsigned*>(&sh.zl[b][2 * k1]) =
                    l0 | (l1 << 16);
            }
        }
        __syncthreads();

        // P2: split-precision MFMA matvec — A from registers
        f32x4 ac1[2] = {{0.f, 0.f, 0.f, 0.f}, {0.f, 0.f, 0.f, 0.f}};
        f32x4 ac2[2] = {{0.f, 0.f, 0.f, 0.f}, {0.f, 0.f, 0.f, 0.f}};
        #pragma unroll
        for (int kt = 0; kt < 4; ++kt) {
            int rg = 128 * s + 32 * kt + 8 * kg;
            half8 bh = *reinterpret_cast<const half8*>(&sh.zh[bB][rg]);
            half8 bl = *reinterpret_cast<const half8*>(&sh.zl[bB][rg]);
            #pragma unroll
            for (int mi = 0; mi < 2; ++mi) {
                ac1[mi] = __builtin_amdgcn_mfma_f32_16x16x32_f16(
                              ahr[kt][mi], bh, ac1[mi], 0, 0, 0);
                ac2[mi] = __builtin_amdgcn_mfma_f32_16x16x32_f16(
                              alr[kt][mi], bh, ac2[mi], 0, 0, 0);
                ac2[mi] = __builtin_amdgcn_mfma_f32_16x16x32_f16(
                              ahr[kt][mi], bl, ac2[mi], 0, 0, 0);
            }
        }

        // contract in-register (linear in w)
        float d0 = 0.f, d1 = 0.f;
        #pragma unroll
        for (int mi = 0; mi < 2; ++mi) {
            int cb = 16 * (mt0 + mi) + 4 * kg;
            float wv0 = fmaf(ac2[mi][0], LOSC, ac1[mi][0]);
            float wv1 = fmaf(ac2[mi][1], LOSC, ac1[mi][1]);
            float wv2 = fmaf(ac2[mi][2], LOSC, ac1[mi][2]);
            float wv3 = fmaf(ac2[mi][3], LOSC, ac1[mi][3]);
            uint2 zhp = *reinterpret_cast<const uint2*>(&sh.zh[bB][cb]);
            uint2 zlp = *reinterpret_cast<const uint2*>(&sh.zl[bB][cb]);
            float z0v = fmaf(__half2float(__ushort_as_half(
                                 (unsigned short)(zlp.x & 0xffff))), LOSC,
                             __half2float(__ushort_as_half(
                                 (unsigned short)(zhp.x & 0xffff))));
            float z1v = fmaf(__half2float(__ushort_as_half(
                                 (unsigned short)(zlp.x >> 16))), LOSC,
                             __half2float(__ushort_as_half(
                                 (unsigned short)(zhp.x >> 16))));
            float z2v = fmaf(__half2float(__ushort_as_half(
                                 (unsigned short)(zlp.y & 0xffff))), LOSC,
                             __half2float(__ushort_as_half(
                                 (unsigned short)(zhp.y & 0xffff))));
            float z3v = fmaf(__half2float(__ushort_as_half(
                                 (unsigned short)(zlp.y >> 16))), LOSC,
                             __half2float(__ushort_as_half(
                                 (unsigned short)(zhp.y >> 16))));
            float g0 = fmaf(wv1, z0v, -wv0 * z1v);
            float g1 = fmaf(wv3, z2v, -wv2 * z3v);
            float4 omq = *reinterpret_cast<const float4*>(&sh.om[cb >> 1]);
            d0 = fmaf(g0, omq.x, d0); d1 = fmaf(g0, omq.y, d1);
            d0 = fmaf(g1, omq.z, d0); d1 = fmaf(g1, omq.w, d1);
        }
        if (cB >= 8) { d0 = 0.f; d1 = 0.f; }   // mask mirrored junk cols

        d0 += __shfl_xor(d0, 16, 64);  d0 += __shfl_xor(d0, 32, 64);
        d1 += __shfl_xor(d1, 16, 64);  d1 += __shfl_xor(d1, 32, 64);
        if (l < 8) {
            sh.wred[w][l]     = d0;
            sh.wred[w][l + 8] = d1;
        }
        __syncthreads();

        // publish / consume (packed u64, R14 protocol)
        unsigned long long* pbuf =
            part + ((size_t)(t & 1) * NG + g) * (NS * 16);
        if (tid < 16) {
            float ssum = 0.f;
            #pragma unroll
            for (int w2 = 0; w2 < 16; ++w2) ssum += sh.wred[w2][tid];
            unsigned long long pk =
                (((unsigned long long)(unsigned)(t + 1)) << 32) |
                (unsigned long long)__float_as_uint(ssum);
            __hip_atomic_store(pbuf + s * 16 + tid, pk,
                               __ATOMIC_RELAXED, __HIP_MEMORY_SCOPE_AGENT);
        }
        float val = 0.f;
        if (tid < 64) {
            int sl = tid >> 4, v = tid & 15;
            unsigned long long* addr = pbuf + sl * 16 + v;
            const unsigned long long tgt =
                ((unsigned long long)(unsigned)(t + 1)) << 32;
            unsigned long long pk;
            for (;;) {
                pk = __hip_atomic_load(addr, __ATOMIC_RELAXED,
                                       __HIP_MEMORY_SCOPE_AGENT);
                if (pk >= tgt) break;
                __builtin_amdgcn_s_sleep(1);
            }
            val = __uint_as_float((unsigned)(pk & 0xffffffffull));
            val += __shfl_xor(val, 16, 64);
            val += __shfl_xor(val, 32, 64);
        }
        if (tid < 16) {
            int b = tid & 7, comp = tid >> 3;
            float pi = reinterpret_cast<const float*>(&sh.dpi[b][t])[comp];
            float dtv = fmaf(DXSC, val, pi);
            Sreg += dtv;
            xreg = fminf(fmaxf(xreg + dtv, 0.f), 2.0f);
            reinterpret_cast<float*>(&sh.x[b])[comp] = xreg;
            sh.Sh[t][b][comp] = Sreg;
            sh.xh[t][b][comp] = xreg;
        }
        __syncthreads();
    }

    // epilogue
    {
        int th2 = tid >> 9, b = (tid >> 6) & 7, kk = tid & 63;
        float2 zp = reinterpret_cast<const float2*>(z0)
                        [(size_t)(b0 + b) * KP + 64 * s + kk];
        float2 o2 = sh.om[64 * s + kk];
        float2* zout = reinterpret_cast<float2*>(z_seq)
                       + (size_t)(b0 + b) * NT * KP + (64 * s + kk);
        for (int tt2 = th2 * 64, e = th2 * 64 + 64; tt2 < e; ++tt2) {
            float Sx = sh.Sh[tt2][b][0], Sy = sh.Sh[tt2][b][1];
            float th = o2.x * Sx + o2.y * Sy;
            float sn, cs;
            __sincosf(th, &sn, &cs);
            zout[(size_t)tt2 * KP] =
                make_float2(cs * zp.x - sn * zp.y, sn * zp.x + cs * zp.y);
        }
    }
    if (s == 0) {
        int b = tid >> 7, tt3 = tid & 127;
        float2 xv = *reinterpret_cast<const float2*>(&sh.xh[tt3][b][0]);
        reinterpret_cast<float2*>(x_seq)[(size_t)(b0 + b) * NT + tt3] = xv;
    }
}

// =================== f32 fallback path (R14, proven) ===================

struct __align__(16) ShmF {
    float  zxc[6400];
    float2 dpi[NB][NT];
    float2 om[KP];
    float2 v[KP];
    float  wred[16][16];
    float  Sh[NT][NB][2];
    float  xh[NT][NB][2];
    float2 x[NB];
    float  nred[16];
    float  pad[7168];
};

__attribute__((amdgpu_flat_work_group_size(1024, 1024),
               amdgpu_waves_per_eu(4, 4)))
__global__ void can_f32(
    const float* __restrict__ dx_pi, const float* __restrict__ z0,
    const float* __restrict__ x0, const float* __restrict__ omega,
    const float* __restrict__ A, const float* __restrict__ z0b,
    float* __restrict__ d_out,
    unsigned long long* __restrict__ part)
{
    __shared__ ShmF sh;
    const int tid = threadIdx.x;
    const int g   = blockIdx.x >> 2;
    const int s   = blockIdx.x & 3;
    const int b0  = NB * g;

    float* z_seq = d_out;
    float* x_seq = d_out + (size_t)512 * NT * DD;

    if (dx_pi == nullptr) ((volatile float*)sh.pad)[0] = 1.f;

    {
        int bb = tid >> 7, tt = tid & 127;
        sh.dpi[bb][tt] =
            reinterpret_cast<const float2*>(dx_pi)[(size_t)(b0 + bb) * NT + tt];
    }
    if (tid < KP) sh.om[tid] = reinterpret_cast<const float2*>(omega)[tid];

    float sq = 0.f;
    if (tid < DD) { float f = z0b[tid]; sq = f * f; }
    #pragma unroll
    for (int o = 1; o < 64; o <<= 1) sq += __shfl_xor(sq, o, 64);
    if ((tid & 63) == 0) sh.nred[tid >> 6] = sq;
    __syncthreads();
    float nsq = 0.f;
    #pragma unroll
    for (int w = 0; w < 16; ++w) nsq += sh.nred[w];
    const float zinv = 1.0f / (sqrtf(nsq) + 1e-5f);
    if (tid < KP) {
        float2 vv = reinterpret_cast<const float2*>(z0b)[tid];
        sh.v[tid] = make_float2(vv.x * zinv, vv.y * zinv);
    }

    float xreg = 0.f, Sreg = 0.f;
    if (tid < 16) {
        int b = tid & 7, comp = tid >> 3;
        xreg = x0[(size_t)(b0 + b) * 2 + comp];
        reinterpret_cast<float*>(&sh.x[b])[comp] = xreg;
    }
    __syncthreads();

    const int rq  = tid >> 6;
    const int cq  = tid & 63;
    const int rg0 = 128 * s + 8 * rq;
    const float4* Ap = reinterpret_cast<const float4*>(A)
                       + (size_t)rg0 * 128 + 2 * cq;
    const int zb  = rofs(rg0);
    const int c0  = 8 * cq;
    const int lane = tid & 63;
    const int s5 = (lane >> 5) & 1, s4 = (lane >> 4) & 1;
    const int s3 = (lane >> 3) & 1, s2 = (lane >> 2) & 1;

    for (int t = 0; t < NT; ++t) {
        {
            int k1 = tid >> 2, bq = tid & 3;
            float2 o2 = sh.om[k1];
            float2 vv = sh.v[k1];
            int ro0 = rofs(2 * k1);
            float a0[2], a1[2];
            #pragma unroll
            for (int j = 0; j < 2; ++j) {
                float2 xb = sh.x[2 * bq + j];
                float th = o2.x * xb.x + o2.y * xb.y;
                float sn, cs;
                __sincosf(th, &sn, &cs);
                a0[j] = cs * vv.x - sn * vv.y;
                a1[j] = sn * vv.x + cs * vv.y;
            }
            *reinterpret_cast<float2*>(&sh.zxc[ro0 + 2 * bq]) =
                make_float2(a0[0], a0[1]);
            *reinterpret_cast<float2*>(&sh.zxc[ro0 + 12 + 2 * bq]) =
                make_float2(a1[0], a1[1]);
        }
        __syncthreads();

        #pragma unroll
        for (int h = 0; h < 2; ++h) {
            float4 accA[4], accB[4];
            #pragma unroll
            for (int c = 0; c < 4; ++c) {
                accA[c] = make_float4(0.f, 0.f, 0.f, 0.f);
                accB[c] = make_float4(0.f, 0.f, 0.f, 0.f);
            }
            #pragma unroll
            for (int jr = 0; jr < 8; ++jr) {
                float4 a = Ap[(size_t)jr * 128 + h];
                float4 zA = *reinterpret_cast<const float4*>(
                                &sh.zxc[zb + 12 * jr]);
                float4 zB = *reinterpret_cast<const float4*>(
                                &sh.zxc[zb + 12 * jr + 4]);
                float aw[4];
                aw[0] = a.x; aw[1] = a.y; aw[2] = a.z; aw[3] = a.w;
                #pragma unroll
                for (int c = 0; c < 4; ++c) {
                    accA[c].x = fmaf(aw[c], zA.x, accA[c].x);
                    accA[c].y = fmaf(aw[c], zA.y, accA[c].y);
                    accA[c].z = fmaf(aw[c], zA.z, accA[c].z);
                    accA[c].w = fmaf(aw[c], zA.w, accA[c].w);
                    accB[c].x = fmaf(aw[c], zB.x, accB[c].x);
                    accB[c].y = fmaf(aw[c], zB.y, accB[c].y);
                    accB[c].z = fmaf(aw[c], zB.z, accB[c].z);
                    accB[c].w = fmaf(aw[c], zB.w, accB[c].w);
                }
            }

            float4 d0A = make_float4(0,0,0,0), d0B = d0A;
            float4 d1A = d0A, d1B = d0A;
            float4 omv = *reinterpret_cast<const float4*>(
                             &sh.om[4 * cq + 2 * h]);
            #pragma unroll
            for (int pp = 0; pp < 2; ++pp) {
                int rl = rofs(c0 + 4 * h + 2 * pp);
                float4 zl0 = *reinterpret_cast<const float4*>(&sh.zxc[rl]);
                float4 zl1 = *reinterpret_cast<const float4*>(&sh.zxc[rl + 4]);
                float4 zh0 = *reinterpret_cast<const float4*>(&sh.zxc[rl + 12]);
                float4 zh1 = *reinterpret_cast<const float4*>(&sh.zxc[rl + 16]);
                float4 wl = accA[2 * pp], wh = accA[2 * pp + 1];
                float4 gl = accB[2 * pp], gh = accB[2 * pp + 1];
                float4 gA, gB;
                gA.x = fmaf(wh.x, zl0.x, -wl.x * zh0.x);
                gA.y = fmaf(wh.y, zl0.y, -wl.y * zh0.y);
                gA.z = fmaf(wh.z, zl0.z, -wl.z * zh0.z);
                gA.w = fmaf(wh.w, zl0.w, -wl.w * zh0.w);
                gB.x = fmaf(gh.x, zl1.x, -gl.x * zh1.x);
                gB.y = fmaf(gh.y, zl1.y, -gl.y * zh1.y);
                gB.z = fmaf(gh.z, zl1.z, -gl.z * zh1.z);
                gB.w = fmaf(gh.w, zl1.w, -gl.w * zh1.w);
                float ox = pp ? omv.z : omv.x;
                float oy = pp ? omv.w : omv.y;
                d0A.x = fmaf(gA.x, ox, d0A.x); d1A.x = fmaf(gA.x, oy, d1A.x);
                d0A.y = fmaf(gA.y, ox, d0A.y); d1A.y = fmaf(gA.y, oy, d1A.y);
                d0A.z = fmaf(gA.z, ox, d0A.z); d1A.z = fmaf(gA.z, oy, d1A.z);
                d0A.w = fmaf(gA.w, ox, d0A.w); d1A.w = fmaf(gA.w, oy, d1A.w);
                d0B.x = fmaf(gB.x, ox, d0B.x); d1B.x = fmaf(gB.x, oy, d1B.x);
                d0B.y = fmaf(gB.y, ox, d0B.y); d1B.y = fmaf(gB.y, oy, d1B.y);
                d0B.z = fmaf(gB.z, ox, d0B.z); d1B.z = fmaf(gB.z, oy, d1B.z);
                d0B.w = fmaf(gB.w, ox, d0B.w); d1B.w = fmaf(gB.w, oy, d1B.w);
            }

            {
                float r_[16];
                *reinterpret_cast<float4*>(&r_[0])  = d0A;
                *reinterpret_cast<float4*>(&r_[4])  = d0B;
                *reinterpret_cast<float4*>(&r_[8])  = d1A;
                *reinterpret_cast<float4*>(&r_[12]) = d1B;
                #pragma unroll
                for (int k = 0; k < 8; ++k) {
                    float snd = s5 ? r_[k] : r_[k + 8];
                    float rcv = __shfl_xor(snd, 32, 64);
                    r_[k] = (s5 ? r_[k + 8] : r_[k]) + rcv;
                }
                #pragma unroll
                for (int k = 0; k < 4; ++k) {
                    float snd = s4 ? r_[k] : r_[k + 4];
                    float rcv = __shfl_xor(snd, 16, 64);
                    r_[k] = (s4 ? r_[k + 4] : r_[k]) + rcv;
                }
                #pragma unroll
                for (int k = 0; k < 2; ++k) {
                    float snd = s3 ? r_[k] : r_[k + 2];
                    float rcv = __shfl_xor(snd, 8, 64);
                    r_[k] = (s3 ? r_[k + 2] : r_[k]) + rcv;
                }
                {
                    float snd = s2 ? r_[0] : r_[1];
                    float rcv = __shfl_xor(snd, 4, 64);
                    r_[0] = (s2 ? r_[1] : r_[0]) + rcv;
                }
                r_[0] += __shfl_xor(r_[0], 2, 64);
                r_[0] += __shfl_xor(r_[0], 1, 64);
                if ((lane & 3) == 0) {
                    if (h == 0) sh.wred[rq][lane >> 2] = r_[0];
                    else        sh.wred[rq][lane >> 2] += r_[0];
                }
            }
        }
        __syncthreads();

        unsigned long long* pbuf =
            part + ((size_t)(t & 1) * NG + g) * (NS * 16);
        if (tid < 16) {
            float ssum = 0.f;
            #pragma unroll
            for (int w = 0; w < 16; ++w) ssum += sh.wred[w][tid];
            unsigned long long pk =
                (((unsigned long long)(unsigned)(t + 1)) << 32) |
                (unsigned long long)__float_as_uint(ssum);
            __hip_atomic_store(pbuf + s * 16 + tid, pk,
                               __ATOMIC_RELAXED, __HIP_MEMORY_SCOPE_AGENT);
        }
        float val = 0.f;
        if (tid < 64) {
            int sl = tid >> 4, v = tid & 15;
            unsigned long long* addr = pbuf + sl * 16 + v;
            const unsigned long long tgt =
                ((unsigned long long)(unsigned)(t + 1)) << 32;
            unsigned long long pk;
            for (;;) {
                pk = __hip_atomic_load(addr, __ATOMIC_RELAXED,
                                       __HIP_MEMORY_SCOPE_AGENT);
                if (pk >= tgt) break;
                __builtin_amdgcn_s_sleep(1);
            }
            val = __uint_as_float((unsigned)(pk & 0xffffffffull));
            val += __shfl_xor(val, 16, 64);
            val += __shfl_xor(val, 32, 64);
        }
        if (tid < 16) {
            int b = tid & 7, comp = tid >> 3;
            float pi = reinterpret_cast<const float*>(&sh.dpi[b][t])[comp];
            float dtv = fmaf(0.1f, val, pi);
            Sreg += dtv;
            xreg = fminf(fmaxf(xreg + dtv, 0.f), 2.0f);
            reinterpret_cast<float*>(&sh.x[b])[comp] = xreg;
            sh.Sh[t][b][comp] = Sreg;
            sh.xh[t][b][comp] = xreg;
        }
        __syncthreads();
    }

    {
        int th2 = tid >> 9, b = (tid >> 6) & 7, kk = tid & 63;
        float2 zp = reinterpret_cast<const float2*>(z0)
                        [(size_t)(b0 + b) * KP + 64 * s + kk];
        float2 o2 = sh.om[64 * s + kk];
        float2* zout = reinterpret_cast<float2*>(z_seq)
                       + (size_t)(b0 + b) * NT * KP + (64 * s + kk);
        for (int tt2 = th2 * 64, e = th2 * 64 + 64; tt2 < e; ++tt2) {
            float Sx = sh.Sh[tt2][b][0], Sy = sh.Sh[tt2][b][1];
            float th = o2.x * Sx + o2.y * Sy;
            float sn, cs;
            __sincosf(th, &sn, &cs);
            zout[(size_t)tt2 * KP] =
                make_float2(cs * zp.x - sn * zp.y, sn * zp.x + cs * zp.y);
        }
    }
    if (s == 0) {
        int b = tid >> 7, tt3 = tid & 127;
        float2 xv = *reinterpret_cast<const float2*>(&sh.xh[tt3][b][0]);
        reinterpret_cast<float2*>(x_seq)[(size_t)(b0 + b) * NT + tt3] = xv;
    }
}

extern "C" void kernel_launch(void* const* d_in, const int* in_sizes, int n_in,
                              void* d_out, int out_size, void* d_ws, size_t ws_size,
                              hipStream_t stream) {
    (void)in_sizes; (void)n_in; (void)out_size;
    unsigned long long* part = reinterpret_cast<unsigned long long*>(d_ws);
    hipMemsetAsync(d_ws, 0, PART_BYTES, stream);   // zero exchange tags

    const size_t need = PART_BYTES + 2 * A16_BYTES;   // 64K + 1M
    if (ws_size >= need) {
        unsigned short* Ah = reinterpret_cast<unsigned short*>(
            reinterpret_cast<char*>(d_ws) + PART_BYTES);
        unsigned short* Al = Ah + (size_t)DD * DD;
        hipLaunchKernelGGL(conv_a, dim3(DD * DD / 512), dim3(512), 0, stream,
                           (const float*)d_in[4], Ah, Al);
        hipLaunchKernelGGL(can_mfma, dim3(NBLK), dim3(1024), 0, stream,
                           (const float*)d_in[0], (const float*)d_in[1],
                           (const float*)d_in[2], (const float*)d_in[3],
                           (const float*)d_in[5], (float*)d_out, part, Ah, Al);
    } else {
        hipLaunchKernelGGL(can_f32, dim3(NBLK), dim3(1024), 0, stream,
                           (const float*)d_in[0], (const float*)d_in[1],
                           (const float*)d_in[2], (const float*)d_in[3],
                           (const float*)d_in[4], (const float*)d_in[5],
                           (float*)d_out, part);
    }
}

// Round 15
// 384.884 us; speedup vs baseline: 1.4696x; 1.0040x over previous
//
#include <hip/hip_runtime.h>
#include <hip/hip_fp16.h>

// CANPathIntegrator — R20: R16 + f32-zx LDS array for the contract.
//
// R19 post-mortem: VGPR stayed 64 AND FETCH stayed 10.9MB -> the
// allocator REMATERIALIZED the hoisted A-fragment loads (loop-invariant,
// L2-hit) instead of holding 128 regs; kernel degenerated to R16 (386 ~
// 380). The 64-reg ceiling is effectively hard. Composed floor: step =
// L2 A-stream 1.8us + serial MALL exchange ~1.1us + P1/reduce ~0.1us.
// One remaining SOFTWARE term: the contract's f16 unpack (8 cvt + 4 fmaf
// per mi x2 x1024 thr ~ 0.2-0.3us/step) exists only because zx lives
// split-f16. P1 computes the exact f32 value before splitting -> store
// it (x256-scaled, so DXSC unchanged) in zxf[8][520] (+8-float row pad
// -> 2-way banks, free) and the contract becomes ds_read_b128 + 2 fmaf.
// +16.6KB LDS (82KB total, still 1 block/CU). All else R16 verbatim.
// Falsifier: dur unchanged => composed floor binding => declare ceiling.
//
// Carried verified structure (R14-R16, absmax 0.0078125):
//   * f16x2 split-precision MFMA: Ah=f16(256A), Al=f16((256A-Ah)*2048);
//     acc1 += Ah*zh, acc2 += Al*zh + Ah*zl; w' = acc1 + acc2/2048;
//     scales fold into DXSC = 0.1*2^-24 (w'~2^16 w, zxf~2^8 zx).
//   * packed-u64 tag-in-data MALL exchange (relaxed, dbuf by t&1).
//   * z_t = R(omega@S_t) z0 epilogue regeneration (rotations commute).
//   * ws guard -> proven R14 f32 kernel (790us) if workspace too small.

typedef __attribute__((ext_vector_type(8))) _Float16 half8;
typedef __attribute__((ext_vector_type(4))) float f32x4;

namespace {
constexpr int NT = 128;
constexpr int DD = 512;
constexpr int KP = 256;
constexpr int NS = 4;      // row slices (128 rows each)
constexpr int NG = 64;     // batch groups
constexpr int NB = 8;      // batches per group
constexpr int NBLK = NG * NS;   // 256 = #CUs
constexpr int ZST = 536;   // zh/zl row stride (shorts)
constexpr int ZFT = 520;   // zxf row stride (floats); 520%32=8 -> spread
constexpr size_t PART_BYTES = (size_t)2 * NG * NS * 16 * 8;   // 64 KB
constexpr size_t A16_BYTES  = (size_t)DD * DD * 2;            // 512 KB each
constexpr float LOSC = 1.0f / 2048.0f;
constexpr float DXSC = 0.1f / 16777216.0f;    // 0.1 * 2^-24

__device__ __forceinline__ int rofs(int r) {   // f32-fallback swizzle
    return 12 * r + 4 * ((r >> 3) & 7) + 32 * (r >> 6);
}
}

// ======================= MFMA path (R20) ==============================

struct __align__(16) ShmM {
    unsigned short zh[NB][ZST];   //  8576 B  f16 hi of 256*zx, [b][r]
    unsigned short zl[NB][ZST];   //  8576 B  f16 lo (x2048 residual)
    float  zxf[NB][ZFT];          // 16640 B  exact f32 256*zx (contract)
    float2 dpi[NB][NT];           //  8192 B
    float2 om[KP];                //  2048 B
    float2 v[KP];                 //  2048 B  z0hat * 256
    float  wred[16][16];          //  1024 B
    float  Sh[NT][NB][2];         //  8192 B
    float  xh[NT][NB][2];         //  8192 B
    float2 x[NB];                 //    64 B
    float  nred[16];              //    64 B
    float  pad[4608];             // 18432 B -> 82048 B total: 1 block/CU
};

__global__ __launch_bounds__(512) void conv_a(
    const float* __restrict__ A,
    unsigned short* __restrict__ Ah, unsigned short* __restrict__ Al)
{
    int i = blockIdx.x * 512 + threadIdx.x;
    float a = A[i] * 256.0f;
    __half h = __float2half(a);
    float r = (a - __half2float(h)) * 2048.0f;
    Ah[i] = __half_as_ushort(h);
    Al[i] = __half_as_ushort(__float2half(r));
}

__attribute__((amdgpu_flat_work_group_size(1024, 1024),
               amdgpu_waves_per_eu(4, 4)))
__global__ void can_mfma(
    const float* __restrict__ dx_pi, const float* __restrict__ z0,
    const float* __restrict__ x0, const float* __restrict__ omega,
    const float* __restrict__ z0b, float* __restrict__ d_out,
    unsigned long long* __restrict__ part,
    const unsigned short* __restrict__ Ah,
    const unsigned short* __restrict__ Al)
{
    __shared__ ShmM sh;
    const int tid = threadIdx.x;
    const int g   = blockIdx.x >> 2;
    const int s   = blockIdx.x & 3;
    const int b0  = NB * g;

    float* z_seq = d_out;
    float* x_seq = d_out + (size_t)512 * NT * DD;

    if (dx_pi == nullptr) ((volatile float*)sh.pad)[0] = 1.f;

    {
        int bb = tid >> 7, tt = tid & 127;
        sh.dpi[bb][tt] =
            reinterpret_cast<const float2*>(dx_pi)[(size_t)(b0 + bb) * NT + tt];
    }
    if (tid < KP) sh.om[tid] = reinterpret_cast<const float2*>(omega)[tid];

    float sq = 0.f;
    if (tid < DD) { float f = z0b[tid]; sq = f * f; }
    #pragma unroll
    for (int o = 1; o < 64; o <<= 1) sq += __shfl_xor(sq, o, 64);
    if ((tid & 63) == 0) sh.nred[tid >> 6] = sq;
    __syncthreads();
    float nsq = 0.f;
    #pragma unroll
    for (int w2 = 0; w2 < 16; ++w2) nsq += sh.nred[w2];
    const float zs = 256.0f / (sqrtf(nsq) + 1e-5f);
    if (tid < KP) {
        float2 vv = reinterpret_cast<const float2*>(z0b)[tid];
        sh.v[tid] = make_float2(vv.x * zs, vv.y * zs);
    }

    float xreg = 0.f, Sreg = 0.f;
    if (tid < 16) {
        int b = tid & 7, comp = tid >> 3;
        xreg = x0[(size_t)(b0 + b) * 2 + comp];
        reinterpret_cast<float*>(&sh.x[b])[comp] = xreg;
    }
    __syncthreads();

    // MFMA roles
    const int w   = tid >> 6;          // wave -> M-tiles 2w, 2w+1
    const int l   = tid & 63;
    const int cB  = l & 15;            // A-frag m / C col
    const int kg  = l >> 4;            // k-chunk 0..3
    const int bB  = l & 7;             // batch (mirrored x2)
    const int mt0 = 2 * w;
    const unsigned short* AhP =
        Ah + (size_t)(16 * mt0 + cB) * DD + (128 * s + 8 * kg);
    const unsigned short* AlP =
        Al + (size_t)(16 * mt0 + cB) * DD + (128 * s + 8 * kg);

    for (int t = 0; t < NT; ++t) {
        // P1: f16-split zx + exact f32 copy for the contract
        {
            int k1 = tid >> 2, bq = tid & 3;
            float2 o2 = sh.om[k1];
            float2 vv = sh.v[k1];
            #pragma unroll
            for (int j = 0; j < 2; ++j) {
                int b = 2 * bq + j;
                float2 xb = sh.x[b];
                float th = o2.x * xb.x + o2.y * xb.y;
                float sn, cs;
                __sincosf(th, &sn, &cs);
                float za  = cs * vv.x - sn * vv.y;   // 256*zx[2k1]
                float zb2 = sn * vv.x + cs * vv.y;   // 256*zx[2k1+1]
                __half h0 = __float2half(za);
                __half h1 = __float2half(zb2);
                unsigned l0 = __half_as_ushort(
                    __float2half((za - __half2float(h0)) * 2048.f));
                unsigned l1 = __half_as_ushort(
                    __float2half((zb2 - __half2float(h1)) * 2048.f));
                *reinterpret_cast<unsigned*>(&sh.zh[b][2 * k1]) =
                    (unsigned)__half_as_ushort(h0) |
                    ((unsigned)__half_as_ushort(h1) << 16);
                *reinterpret_cast<unsigned*>(&sh.zl[b][2 * k1]) =
                    l0 | (l1 << 16);
                *reinterpret_cast<float2*>(&sh.zxf[b][2 * k1]) =
                    make_float2(za, zb2);
            }
        }
        __syncthreads();

        // P2: split-precision MFMA matvec (A streamed from L2)
        f32x4 ac1[2] = {{0.f, 0.f, 0.f, 0.f}, {0.f, 0.f, 0.f, 0.f}};
        f32x4 ac2[2] = {{0.f, 0.f, 0.f, 0.f}, {0.f, 0.f, 0.f, 0.f}};
        #pragma unroll
        for (int kt = 0; kt < 4; ++kt) {
            int rg = 128 * s + 32 * kt + 8 * kg;
            half8 bh = *reinterpret_cast<const half8*>(&sh.zh[bB][rg]);
            half8 bl = *reinterpret_cast<const half8*>(&sh.zl[bB][rg]);
            #pragma unroll
            for (int mi = 0; mi < 2; ++mi) {
                half8 ah = *reinterpret_cast<const half8*>(
                               AhP + (size_t)mi * 16 * DD + 32 * kt);
                half8 al = *reinterpret_cast<const half8*>(
                               AlP + (size_t)mi * 16 * DD + 32 * kt);
                ac1[mi] = __builtin_amdgcn_mfma_f32_16x16x32_f16(
                              ah, bh, ac1[mi], 0, 0, 0);
                ac2[mi] = __builtin_amdgcn_mfma_f32_16x16x32_f16(
                              al, bh, ac2[mi], 0, 0, 0);
                ac2[mi] = __builtin_amdgcn_mfma_f32_16x16x32_f16(
                              ah, bl, ac2[mi], 0, 0, 0);
            }
        }

        // contract in-register (linear in w); zx from exact f32 LDS
        float d0 = 0.f, d1 = 0.f;
        #pragma unroll
        for (int mi = 0; mi < 2; ++mi) {
            int cb = 16 * (mt0 + mi) + 4 * kg;
            float wv0 = fmaf(ac2[mi][0], LOSC, ac1[mi][0]);
            float wv1 = fmaf(ac2[mi][1], LOSC, ac1[mi][1]);
            float wv2 = fmaf(ac2[mi][2], LOSC, ac1[mi][2]);
            float wv3 = fmaf(ac2[mi][3], LOSC, ac1[mi][3]);
            float4 zq = *reinterpret_cast<const float4*>(&sh.zxf[bB][cb]);
            float g0 = fmaf(wv1, zq.x, -wv0 * zq.y);
            float g1 = fmaf(wv3, zq.z, -wv2 * zq.w);
            float4 omq = *reinterpret_cast<const float4*>(&sh.om[cb >> 1]);
            d0 = fmaf(g0, omq.x, d0); d1 = fmaf(g0, omq.y, d1);
            d0 = fmaf(g1, omq.z, d0); d1 = fmaf(g1, omq.w, d1);
        }
        if (cB >= 8) { d0 = 0.f; d1 = 0.f; }   // mask mirrored junk cols

        d0 += __shfl_xor(d0, 16, 64);  d0 += __shfl_xor(d0, 32, 64);
        d1 += __shfl_xor(d1, 16, 64);  d1 += __shfl_xor(d1, 32, 64);
        if (l < 8) {
            sh.wred[w][l]     = d0;
            sh.wred[w][l + 8] = d1;
        }
        __syncthreads();

        // publish / consume (packed u64, R14 protocol)
        unsigned long long* pbuf =
            part + ((size_t)(t & 1) * NG + g) * (NS * 16);
        if (tid < 16) {
            float ssum = 0.f;
            #pragma unroll
            for (int w2 = 0; w2 < 16; ++w2) ssum += sh.wred[w2][tid];
            unsigned long long pk =
                (((unsigned long long)(unsigned)(t + 1)) << 32) |
                (unsigned long long)__float_as_uint(ssum);
            __hip_atomic_store(pbuf + s * 16 + tid, pk,
                               __ATOMIC_RELAXED, __HIP_MEMORY_SCOPE_AGENT);
        }
        float val = 0.f;
        if (tid < 64) {
            int sl = tid >> 4, v = tid & 15;
            unsigned long long* addr = pbuf + sl * 16 + v;
            const unsigned long long tgt =
                ((unsigned long long)(unsigned)(t + 1)) << 32;
            unsigned long long pk;
            for (;;) {
                pk = __hip_atomic_load(addr, __ATOMIC_RELAXED,
                                       __HIP_MEMORY_SCOPE_AGENT);
                if (pk >= tgt) break;
                __builtin_amdgcn_s_sleep(1);
            }
            val = __uint_as_float((unsigned)(pk & 0xffffffffull));
            val += __shfl_xor(val, 16, 64);
            val += __shfl_xor(val, 32, 64);
        }
        if (tid < 16) {
            int b = tid & 7, comp = tid >> 3;
            float pi = reinterpret_cast<const float*>(&sh.dpi[b][t])[comp];
            float dtv = fmaf(DXSC, val, pi);
            Sreg += dtv;
            xreg = fminf(fmaxf(xreg + dtv, 0.f), 2.0f);
            reinterpret_cast<float*>(&sh.x[b])[comp] = xreg;
            sh.Sh[t][b][comp] = Sreg;
            sh.xh[t][b][comp] = xreg;
        }
        __syncthreads();
    }

    // epilogue
    {
        int th2 = tid >> 9, b = (tid >> 6) & 7, kk = tid & 63;
        float2 zp = reinterpret_cast<const float2*>(z0)
                        [(size_t)(b0 + b) * KP + 64 * s + kk];
        float2 o2 = sh.om[64 * s + kk];
        float2* zout = reinterpret_cast<float2*>(z_seq)
                       + (size_t)(b0 + b) * NT * KP + (64 * s + kk);
        for (int tt2 = th2 * 64, e = th2 * 64 + 64; tt2 < e; ++tt2) {
            float Sx = sh.Sh[tt2][b][0], Sy = sh.Sh[tt2][b][1];
            float th = o2.x * Sx + o2.y * Sy;
            float sn, cs;
            __sincosf(th, &sn, &cs);
            zout[(size_t)tt2 * KP] =
                make_float2(cs * zp.x - sn * zp.y, sn * zp.x + cs * zp.y);
        }
    }
    if (s == 0) {
        int b = tid >> 7, tt3 = tid & 127;
        float2 xv = *reinterpret_cast<const float2*>(&sh.xh[tt3][b][0]);
        reinterpret_cast<float2*>(x_seq)[(size_t)(b0 + b) * NT + tt3] = xv;
    }
}

// =================== f32 fallback path (R14, proven) ===================

struct __align__(16) ShmF {
    float  zxc[6400];
    float2 dpi[NB][NT];
    float2 om[KP];
    float2 v[KP];
    float  wred[16][16];
    float  Sh[NT][NB][2];
    float  xh[NT][NB][2];
    float2 x[NB];
    float  nred[16];
    float  pad[7168];
};

__attribute__((amdgpu_flat_work_group_size(1024, 1024),
               amdgpu_waves_per_eu(4, 4)))
__global__ void can_f32(
    const float* __restrict__ dx_pi, const float* __restrict__ z0,
    const float* __restrict__ x0, const float* __restrict__ omega,
    const float* __restrict__ A, const float* __restrict__ z0b,
    float* __restrict__ d_out,
    unsigned long long* __restrict__ part)
{
    __shared__ ShmF sh;
    const int tid = threadIdx.x;
    const int g   = blockIdx.x >> 2;
    const int s   = blockIdx.x & 3;
    const int b0  = NB * g;

    float* z_seq = d_out;
    float* x_seq = d_out + (size_t)512 * NT * DD;

    if (dx_pi == nullptr) ((volatile float*)sh.pad)[0] = 1.f;

    {
        int bb = tid >> 7, tt = tid & 127;
        sh.dpi[bb][tt] =
            reinterpret_cast<const float2*>(dx_pi)[(size_t)(b0 + bb) * NT + tt];
    }
    if (tid < KP) sh.om[tid] = reinterpret_cast<const float2*>(omega)[tid];

    float sq = 0.f;
    if (tid < DD) { float f = z0b[tid]; sq = f * f; }
    #pragma unroll
    for (int o = 1; o < 64; o <<= 1) sq += __shfl_xor(sq, o, 64);
    if ((tid & 63) == 0) sh.nred[tid >> 6] = sq;
    __syncthreads();
    float nsq = 0.f;
    #pragma unroll
    for (int w = 0; w < 16; ++w) nsq += sh.nred[w];
    const float zinv = 1.0f / (sqrtf(nsq) + 1e-5f);
    if (tid < KP) {
        float2 vv = reinterpret_cast<const float2*>(z0b)[tid];
        sh.v[tid] = make_float2(vv.x * zinv, vv.y * zinv);
    }

    float xreg = 0.f, Sreg = 0.f;
    if (tid < 16) {
        int b = tid & 7, comp = tid >> 3;
        xreg = x0[(size_t)(b0 + b) * 2 + comp];
        reinterpret_cast<float*>(&sh.x[b])[comp] = xreg;
    }
    __syncthreads();

    const int rq  = tid >> 6;
    const int cq  = tid & 63;
    const int rg0 = 128 * s + 8 * rq;
    const float4* Ap = reinterpret_cast<const float4*>(A)
                       + (size_t)rg0 * 128 + 2 * cq;
    const int zb  = rofs(rg0);
    const int c0  = 8 * cq;
    const int lane = tid & 63;
    const int s5 = (lane >> 5) & 1, s4 = (lane >> 4) & 1;
    const int s3 = (lane >> 3) & 1, s2 = (lane >> 2) & 1;

    for (int t = 0; t < NT; ++t) {
        {
            int k1 = tid >> 2, bq = tid & 3;
            float2 o2 = sh.om[k1];
            float2 vv = sh.v[k1];
            int ro0 = rofs(2 * k1);
            float a0[2], a1[2];
            #pragma unroll
            for (int j = 0; j < 2; ++j) {
                float2 xb = sh.x[2 * bq + j];
                float th = o2.x * xb.x + o2.y * xb.y;
                float sn, cs;
                __sincosf(th, &sn, &cs);
                a0[j] = cs * vv.x - sn * vv.y;
                a1[j] = sn * vv.x + cs * vv.y;
            }
            *reinterpret_cast<float2*>(&sh.zxc[ro0 + 2 * bq]) =
                make_float2(a0[0], a0[1]);
            *reinterpret_cast<float2*>(&sh.zxc[ro0 + 12 + 2 * bq]) =
                make_float2(a1[0], a1[1]);
        }
        __syncthreads();

        #pragma unroll
        for (int h = 0; h < 2; ++h) {
            float4 accA[4], accB[4];
            #pragma unroll
            for (int c = 0; c < 4; ++c) {
                accA[c] = make_float4(0.f, 0.f, 0.f, 0.f);
                accB[c] = make_float4(0.f, 0.f, 0.f, 0.f);
            }
            #pragma unroll
            for (int jr = 0; jr < 8; ++jr) {
                float4 a = Ap[(size_t)jr * 128 + h];
                float4 zA = *reinterpret_cast<const float4*>(
                                &sh.zxc[zb + 12 * jr]);
                float4 zB = *reinterpret_cast<const float4*>(
                                &sh.zxc[zb + 12 * jr + 4]);
                float aw[4];
                aw[0] = a.x; aw[1] = a.y; aw[2] = a.z; aw[3] = a.w;
                #pragma unroll
                for (int c = 0; c < 4; ++c) {
                    accA[c].x = fmaf(aw[c], zA.x, accA[c].x);
                    accA[c].y = fmaf(aw[c], zA.y, accA[c].y);
                    accA[c].z = fmaf(aw[c], zA.z, accA[c].z);
                    accA[c].w = fmaf(aw[c], zA.w, accA[c].w);
                    accB[c].x = fmaf(aw[c], zB.x, accB[c].x);
                    accB[c].y = fmaf(aw[c], zB.y, accB[c].y);
                    accB[c].z = fmaf(aw[c], zB.z, accB[c].z);
                    accB[c].w = fmaf(aw[c], zB.w, accB[c].w);
                }
            }

            float4 d0A = make_float4(0,0,0,0), d0B = d0A;
            float4 d1A = d0A, d1B = d0A;
            float4 omv = *reinterpret_cast<const float4*>(
                             &sh.om[4 * cq + 2 * h]);
            #pragma unroll
            for (int pp = 0; pp < 2; ++pp) {
                int rl = rofs(c0 + 4 * h + 2 * pp);
                float4 zl0 = *reinterpret_cast<const float4*>(&sh.zxc[rl]);
                float4 zl1 = *reinterpret_cast<const float4*>(&sh.zxc[rl + 4]);
                float4 zh0 = *reinterpret_cast<const float4*>(&sh.zxc[rl + 12]);
                float4 zh1 = *reinterpret_cast<const float4*>(&sh.zxc[rl + 16]);
                float4 wl = accA[2 * pp], wh = accA[2 * pp + 1];
                float4 gl = accB[2 * pp], gh = accB[2 * pp + 1];
                float4 gA, gB;
                gA.x = fmaf(wh.x, zl0.x, -wl.x * zh0.x);
                gA.y = fmaf(wh.y, zl0.y, -wl.y * zh0.y);
                gA.z = fmaf(wh.z, zl0.z, -wl.z * zh0.z);
                gA.w = fmaf(wh.w, zl0.w, -wl.w * zh0.w);
                gB.x = fmaf(gh.x, zl1.x, -gl.x * zh1.x);
                gB.y = fmaf(gh.y, zl1.y, -gl.y * zh1.y);
                gB.z = fmaf(gh.z, zl1.z, -gl.z * zh1.z);
                gB.w = fmaf(gh.w, zl1.w, -gl.w * zh1.w);
                float ox = pp ? omv.z : omv.x;
                float oy = pp ? omv.w : omv.y;
                d0A.x = fmaf(gA.x, ox, d0A.x); d1A.x = fmaf(gA.x, oy, d1A.x);
                d0A.y = fmaf(gA.y, ox, d0A.y); d1A.y = fmaf(gA.y, oy, d1A.y);
                d0A.z = fmaf(gA.z, ox, d0A.z); d1A.z = fmaf(gA.z, oy, d1A.z);
                d0A.w = fmaf(gA.w, ox, d0A.w); d1A.w = fmaf(gA.w, oy, d1A.w);
                d0B.x = fmaf(gB.x, ox, d0B.x); d1B.x = fmaf(gB.x, oy, d1B.x);
                d0B.y = fmaf(gB.y, ox, d0B.y); d1B.y = fmaf(gB.y, oy, d1B.y);
                d0B.z = fmaf(gB.z, ox, d0B.z); d1B.z = fmaf(gB.z, oy, d1B.z);
                d0B.w = fmaf(gB.w, ox, d0B.w); d1B.w = fmaf(gB.w, oy, d1B.w);
            }

            {
                float r_[16];
                *reinterpret_cast<float4*>(&r_[0])  = d0A;
                *reinterpret_cast<float4*>(&r_[4])  = d0B;
                *reinterpret_cast<float4*>(&r_[8])  = d1A;
                *reinterpret_cast<float4*>(&r_[12]) = d1B;
                #pragma unroll
                for (int k = 0; k < 8; ++k) {
                    float snd = s5 ? r_[k] : r_[k + 8];
                    float rcv = __shfl_xor(snd, 32, 64);
                    r_[k] = (s5 ? r_[k + 8] : r_[k]) + rcv;
                }
                #pragma unroll
                for (int k = 0; k < 4; ++k) {
                    float snd = s4 ? r_[k] : r_[k + 4];
                    float rcv = __shfl_xor(snd, 16, 64);
                    r_[k] = (s4 ? r_[k + 4] : r_[k]) + rcv;
                }
                #pragma unroll
                for (int k = 0; k < 2; ++k) {
                    float snd = s3 ? r_[k] : r_[k + 2];
                    float rcv = __shfl_xor(snd, 8, 64);
                    r_[k] = (s3 ? r_[k + 2] : r_[k]) + rcv;
                }
                {
                    float snd = s2 ? r_[0] : r_[1];
                    float rcv = __shfl_xor(snd, 4, 64);
                    r_[0] = (s2 ? r_[1] : r_[0]) + rcv;
                }
                r_[0] += __shfl_xor(r_[0], 2, 64);
                r_[0] += __shfl_xor(r_[0], 1, 64);
                if ((lane & 3) == 0) {
                    if (h == 0) sh.wred[rq][lane >> 2] = r_[0];
                    else        sh.wred[rq][lane >> 2] += r_[0];
                }
            }
        }
        __syncthreads();

        unsigned long long* pbuf =
            part + ((size_t)(t & 1) * NG + g) * (NS * 16);
        if (tid < 16) {
            float ssum = 0.f;
            #pragma unroll
            for (int w = 0; w < 16; ++w) ssum += sh.wred[w][tid];
            unsigned long long pk =
                (((unsigned long long)(unsigned)(t + 1)) << 32) |
                (unsigned long long)__float_as_uint(ssum);
            __hip_atomic_store(pbuf + s * 16 + tid, pk,
                               __ATOMIC_RELAXED, __HIP_MEMORY_SCOPE_AGENT);
        }
        float val = 0.f;
        if (tid < 64) {
            int sl = tid >> 4, v = tid & 15;
            unsigned long long* addr = pbuf + sl * 16 + v;
            const unsigned long long tgt =
                ((unsigned long long)(unsigned)(t + 1)) << 32;
            unsigned long long pk;
            for (;;) {
                pk = __hip_atomic_load(addr, __ATOMIC_RELAXED,
                                       __HIP_MEMORY_SCOPE_AGENT);
                if (pk >= tgt) break;
                __builtin_amdgcn_s_sleep(1);
            }
            val = __uint_as_float((unsigned)(pk & 0xffffffffull));
            val += __shfl_xor(val, 16, 64);
            val += __shfl_xor(val, 32, 64);
        }
        if (tid < 16) {
            int b = tid & 7, comp = tid >> 3;
            float pi = reinterpret_cast<const float*>(&sh.dpi[b][t])[comp];
            float dtv = fmaf(0.1f, val, pi);
            Sreg += dtv;
            xreg = fminf(fmaxf(xreg + dtv, 0.f), 2.0f);
            reinterpret_cast<float*>(&sh.x[b])[comp] = xreg;
            sh.Sh[t][b][comp] = Sreg;
            sh.xh[t][b][comp] = xreg;
        }
        __syncthreads();
    }

    {
        int th2 = tid >> 9, b = (tid >> 6) & 7, kk = tid & 63;
        float2 zp = reinterpret_cast<const float2*>(z0)
                        [(size_t)(b0 + b) * KP + 64 * s + kk];
        float2 o2 = sh.om[64 * s + kk];
        float2* zout = reinterpret_cast<float2*>(z_seq)
                       + (size_t)(b0 + b) * NT * KP + (64 * s + kk);
        for (int tt2 = th2 * 64, e = th2 * 64 + 64; tt2 < e; ++tt2) {
            float Sx = sh.Sh[tt2][b][0], Sy = sh.Sh[tt2][b][1];
            float th = o2.x * Sx + o2.y * Sy;
            float sn, cs;
            __sincosf(th, &sn, &cs);
            zout[(size_t)tt2 * KP] =
                make_float2(cs * zp.x - sn * zp.y, sn * zp.x + cs * zp.y);
        }
    }
    if (s == 0) {
        int b = tid >> 7, tt3 = tid & 127;
        float2 xv = *reinterpret_cast<const float2*>(&sh.xh[tt3][b][0]);
        reinterpret_cast<float2*>(x_seq)[(size_t)(b0 + b) * NT + tt3] = xv;
    }
}

extern "C" void kernel_launch(void* const* d_in, const int* in_sizes, int n_in,
                              void* d_out, int out_size, void* d_ws, size_t ws_size,
                              hipStream_t stream) {
    (void)in_sizes; (void)n_in; (void)out_size;
    unsigned long long* part = reinterpret_cast<unsigned long long*>(d_ws);
    hipMemsetAsync(d_ws, 0, PART_BYTES, stream);   // zero exchange tags

    const size_t need = PART_BYTES + 2 * A16_BYTES;   // 64K + 1M
    if (ws_size >= need) {
        unsigned short* Ah = reinterpret_cast<unsigned short*>(
            reinterpret_cast<char*>(d_ws) + PART_BYTES);
        unsigned short* Al = Ah + (size_t)DD * DD;
        hipLaunchKernelGGL(conv_a, dim3(DD * DD / 512), dim3(512), 0, stream,
                           (const float*)d_in[4], Ah, Al);
        hipLaunchKernelGGL(can_mfma, dim3(NBLK), dim3(1024), 0, stream,
                           (const float*)d_in[0], (const float*)d_in[1],
                           (const float*)d_in[2], (const float*)d_in[3],
                           (const float*)d_in[5], (float*)d_out, part, Ah, Al);
    } else {
        hipLaunchKernelGGL(can_f32, dim3(NBLK), dim3(1024), 0, stream,
                           (const float*)d_in[0], (const float*)d_in[1],
                           (const float*)d_in[2], (const float*)d_in[3],
                           (const float*)d_in[4], (const float*)d_in[5],
                           (float*)d_out, part);
    }
}